// Round 11
// baseline (54406.439 us; speedup 1.0000x reference)
//
#include <hip/hip_runtime.h>
#include <stdint.h>

#define S_LEN 16384
#define HID 2048
#define NPAIR 1024   // h pairs (2048/2)
#define NGRP 8       // XCD groups (blk % 8 under round-robin dispatch)

typedef _Float16 h2v __attribute__((ext_vector_type(2)));

__device__ __forceinline__ float dot2f(uint32_t a, uint32_t b, float c) {
#if __has_builtin(__builtin_amdgcn_fdot2)
  return __builtin_amdgcn_fdot2(__builtin_bit_cast(h2v, a), __builtin_bit_cast(h2v, b), c, false);
#else
  h2v ha = __builtin_bit_cast(h2v, a), hb = __builtin_bit_cast(h2v, b);
  return c + (float)ha[0] * (float)hb[0] + (float)ha[1] * (float)hb[1];
#endif
}

__device__ __forceinline__ uint32_t packh2(float a, float b) {
  h2v h; h[0] = (_Float16)a; h[1] = (_Float16)b;
  return __builtin_bit_cast(uint32_t, h);
}

__device__ __forceinline__ float fsig(float x) { return 1.0f / (1.0f + __expf(-x)); }
__device__ __forceinline__ float ftanh(float x) { return 2.0f / (1.0f + __expf(-2.0f * x)) - 1.0f; }

// L2-scope (sc0-only) ops: bypass L1, served by the XCD's L2, never forced to
// MALL. Used for intra-XCD relay->consumer fanout. If producer and consumer
// are NOT on the same XCD these may never show fresh data — the calling loop
// always has an agent-scope fallback, so correctness holds.
__device__ __forceinline__ void ld_l2_pair(const unsigned long long* p0,
                                           const unsigned long long* p1,
                                           unsigned long long& v0,
                                           unsigned long long& v1) {
  asm volatile("global_load_dwordx2 %0, %2, off sc0\n\t"
               "global_load_dwordx2 %1, %3, off sc0\n\t"
               "s_waitcnt vmcnt(0)"
               : "=&v"(v0), "=&v"(v1)
               : "v"(p0), "v"(p1)
               : "memory");
}
__device__ __forceinline__ void st_l2(unsigned long long* p, unsigned long long v) {
  asm volatile("global_store_dwordx2 %0, %1, off sc0" : : "v"(p), "v"(v) : "memory");
}

// Wave64 sum via DPP (VALU pipe only, no DS ops). Valid result in lane 63.
__device__ __forceinline__ float wave_reduce_add(float x) {
#define DPP_STEP(ctrl)                                                                   \
  {                                                                                      \
    int t_ = __builtin_amdgcn_update_dpp(0, __builtin_bit_cast(int, x), ctrl, 0xf, 0xf, true); \
    x += __builtin_bit_cast(float, t_);                                                  \
  }
  DPP_STEP(0x111)  // row_shr:1
  DPP_STEP(0x112)  // row_shr:2
  DPP_STEP(0x114)  // row_shr:4
  DPP_STEP(0x118)  // row_shr:8
  DPP_STEP(0x142)  // row_bcast:15
  DPP_STEP(0x143)  // row_bcast:31
#undef DPP_STEP
  return x;
}

// ---------------- Phase A: QCNN MLP per token + hbuf/lbuf init ----------------
__global__ __launch_bounds__(256) void qcnn_kernel(
    const float* __restrict__ sent,
    const float* __restrict__ fm_w, const float* __restrict__ fm_b,
    const float* __restrict__ c1w, const float* __restrict__ c1b,
    const float* __restrict__ p1w, const float* __restrict__ p1b,
    const float* __restrict__ c2w, const float* __restrict__ c2b,
    const float* __restrict__ p2w, const float* __restrict__ p2b,
    const float* __restrict__ c3w, const float* __restrict__ c3b,
    const float* __restrict__ hw, const float* __restrict__ hb,
    float* __restrict__ seq, unsigned long long* __restrict__ hbuf,
    unsigned long long* __restrict__ lbuf) {
  __shared__ float w[720];
  const int tid = threadIdx.x;
  const float* srcs[14] = {fm_w, fm_b, c1w, c1b, p1w, p1b, c2w, c2b, p2w, p2b, c3w, c3b, hw, hb};
  const int offs[14] = {0, 128, 144, 400, 416, 608, 620, 668, 672, 688, 692, 708, 712, 716};
  const int cnts[14] = {128, 16, 256, 16, 192, 12, 48, 4, 16, 4, 16, 4, 4, 1};
  for (int a = 0; a < 14; ++a)
    for (int i = tid; i < cnts[a]; i += 256) w[offs[a] + i] = srcs[a][i];
  if (blockIdx.x == 0) {
    // slot = u64: (tag32 << 32) | f16x2 pair. step s consumes tag s.
    // parity0 (even steps): tag 0, h(-1)=0; parity1: invalid tag.
    for (int p = tid; p < NPAIR; p += 256) {
      hbuf[p] = 0ull;
      hbuf[NPAIR + p] = 0x7FFFFFFFull << 32;
    }
    for (int idx = tid; idx < NGRP * NPAIR; idx += 256) {
      const int g = idx >> 10, i = idx & (NPAIR - 1);
      lbuf[(size_t)(g * 2) * NPAIR + i] = 0ull;
      lbuf[(size_t)(g * 2 + 1) * NPAIR + i] = 0x7FFFFFFFull << 32;
    }
  }
  __syncthreads();
  const int t = blockIdx.x * 256 + tid;
  float x[8];
#pragma unroll
  for (int i = 0; i < 8; ++i) x[i] = sent[t * 8 + i];
  float a0[16], a1[16], a2[12], a3[4], a4[4], a5[4];
#pragma unroll
  for (int o = 0; o < 16; ++o) {
    float s = w[128 + o];
#pragma unroll
    for (int i = 0; i < 8; ++i) s += x[i] * w[i * 16 + o];
    a0[o] = ftanh(s);
  }
#pragma unroll
  for (int o = 0; o < 16; ++o) {
    float s = w[400 + o];
#pragma unroll
    for (int i = 0; i < 16; ++i) s += a0[i] * w[144 + i * 16 + o];
    a1[o] = ftanh(s);
  }
#pragma unroll
  for (int o = 0; o < 12; ++o) {
    float s = w[608 + o];
#pragma unroll
    for (int i = 0; i < 16; ++i) s += a1[i] * w[416 + i * 12 + o];
    a2[o] = ftanh(s);
  }
#pragma unroll
  for (int o = 0; o < 4; ++o) {
    float s = w[668 + o];
#pragma unroll
    for (int i = 0; i < 12; ++i) s += a2[i] * w[620 + i * 4 + o];
    a3[o] = ftanh(s);
  }
#pragma unroll
  for (int o = 0; o < 4; ++o) {
    float s = w[688 + o];
#pragma unroll
    for (int i = 0; i < 4; ++i) s += a3[i] * w[672 + i * 4 + o];
    a4[o] = ftanh(s);
  }
#pragma unroll
  for (int o = 0; o < 4; ++o) {
    float s = w[708 + o];
#pragma unroll
    for (int i = 0; i < 4; ++i) s += a4[i] * w[692 + i * 4 + o];
    a5[o] = ftanh(s);
  }
  float s = w[716];
#pragma unroll
  for (int i = 0; i < 4; ++i) s += a5[i] * w[712 + i];
  seq[t] = fsig(s);
}

// ---------------- Phase B: persistent LSTM scan (XCD relay broadcast) ----------------
// 256 blocks x 512 threads (8 waves). Wave wv owns hidden unit col = blk*8+wv.
// Weights in VGPRs. Group g = blk & 7 (round-robin => same XCD). Blocks 0..7
// are per-group relays: they poll global hbuf with a NO-SLEEP rotating 2-pair
// poll (8 MALL pollers device-wide) and fan tagged u64s into lbuf[g][parity]
// with sc0 stores (XCD-L2-resident). Consumers poll lbuf with a dense
// single-waitcnt sc0 pair-load (~300cy period) and fall back to agent-scope
// global checks every 8th iteration (placement-independent correctness).
__global__ __launch_bounds__(512, 2) void lstm_kernel(
    const float* __restrict__ seq,
    const float* __restrict__ wfp, const float* __restrict__ bfp,
    const float* __restrict__ wip, const float* __restrict__ bip,
    const float* __restrict__ wup, const float* __restrict__ bup,
    const float* __restrict__ wop, const float* __restrict__ bop,
    unsigned long long* __restrict__ hbuf,
    unsigned long long* __restrict__ lbuf,
    uint32_t* __restrict__ hseq) {
  __shared__ __align__(16) uint32_t smem[32768];  // 128 KB
  const int tid = threadIdx.x;
  const int lane = tid & 63;
  const int wv = tid >> 6;  // 0..7
  const int blk = blockIdx.x;
  const int grp = blk & (NGRP - 1);
  const bool is_relay = (blk < NGRP);
  const int col = blk * 8 + wv;
  const float* wptr[4] = {wfp, wip, wup, wop};
  const float* bptr[4] = {bfp, bip, bup, bop};

  // ---- stage packed-f16 weights into LDS (temporary) ----
  {
    const int jj = tid & 7;
    const int sc = blk * 8 + jj;
    const int pb = tid >> 3;  // 0..63
#pragma unroll
    for (int g = 0; g < 4; ++g) {
      const float* wsp = wptr[g];
      for (int pp = 0; pp < 16; ++pp) {
        int p = pp * 64 + pb;
        float w0 = wsp[(size_t)(1 + 2 * p) * HID + sc];
        float w1 = wsp[(size_t)(2 + 2 * p) * HID + sc];
        smem[(jj * 1024 + p) * 4 + g] = packh2(w0, w1);
      }
    }
  }
  __syncthreads();
  // ---- LDS -> VGPRs: wr[m][j][g] = gate-g weight pair (256m + 4*lane + j) ----
  uint32_t wr[4][4][4];
#pragma unroll
  for (int m = 0; m < 4; ++m)
#pragma unroll
    for (int j = 0; j < 4; ++j) {
      const uint4 q = *(const uint4*)&smem[(wv * 1024 + 256 * m + 4 * lane + j) * 4];
      wr[m][j][0] = q.x; wr[m][j][1] = q.y; wr[m][j][2] = q.z; wr[m][j][3] = q.w;
    }
  float wx[4], bb[4];
#pragma unroll
  for (int g = 0; g < 4; ++g) {
    wx[g] = wptr[g][col];  // row 0 = x coefficient
    bb[g] = bptr[g][col];
  }
  __syncthreads();
  // ---- repurpose LDS: [0,64K) = seq, [64K,72K) = h pair double buffer, then hx ----
  float* seqf = (float*)smem;
  for (int i = tid; i < 4096; i += 512) ((float4*)seqf)[i] = ((const float4*)seq)[i];
  uint32_t* hlds = smem + 16384;                   // 2 x 1024 u32 pairs
  uint16_t* hx16 = (uint16_t*)(smem + 18432);      // 8 x u16
  __syncthreads();

#define LDP(p) __hip_atomic_load((p), __ATOMIC_RELAXED, __HIP_MEMORY_SCOPE_AGENT)

  float cell = 0.f;
  for (int s = 0; s < S_LEN; ++s) {
    const int slot = s & 1;
    uint32_t* hl = hlds + slot * NPAIR;
    const float xt = seqf[s];
    const uint32_t want = (uint32_t)s;
    unsigned long long hv0, hv1;
    if (is_relay) {
      // -- relay: NO-SLEEP rotating 2-pair poll of my global 128-pair window --
      unsigned long long* src = hbuf + (size_t)slot * NPAIR + wv * 128 + lane;
      unsigned long long A0 = LDP(src), A1 = LDP(src + 64);
      unsigned long long B0 = LDP(src), B1 = LDP(src + 64);
      while (true) {
        const bool okA = ((uint32_t)(A0 >> 32) == want) & ((uint32_t)(A1 >> 32) == want);
        if (__all(okA)) { hv0 = A0; hv1 = A1; break; }
        A0 = LDP(src); A1 = LDP(src + 64);
        const bool okB = ((uint32_t)(B0 >> 32) == want) & ((uint32_t)(B1 >> 32) == want);
        if (__all(okB)) { hv0 = B0; hv1 = B1; break; }
        B0 = LDP(src); B1 = LDP(src + 64);
      }
      // -- fan out into this XCD's local buffer (L2-resident, fire-and-forget) --
      unsigned long long* ldst = lbuf + (size_t)(grp * 2 + slot) * NPAIR + wv * 128 + lane;
      st_l2(ldst, hv0);
      st_l2(ldst + 64, hv1);
    } else {
      // -- consumer: dense L2-local pair-poll (one waitcnt), amortized fallback --
      const unsigned long long* lsrc =
          lbuf + (size_t)(grp * 2 + slot) * NPAIR + wv * 128 + lane;
      unsigned long long* gsrc = hbuf + (size_t)slot * NPAIR + wv * 128 + lane;
      bool d0 = false, d1 = false;
      unsigned long long h0 = 0, h1 = 0;
      int it = 0;
      while (true) {
        unsigned long long t0, t1;
        ld_l2_pair(lsrc, lsrc + 64, t0, t1);
        if (!d0 && (uint32_t)(t0 >> 32) == want) { h0 = t0; d0 = true; }
        if (!d1 && (uint32_t)(t1 >> 32) == want) { h1 = t1; d1 = true; }
        if (__all(d0 && d1)) break;
        if ((++it & 7) == 0) {
          unsigned long long g0 = LDP(gsrc), g1 = LDP(gsrc + 64);
          if (!d0 && (uint32_t)(g0 >> 32) == want) { h0 = g0; d0 = true; }
          if (!d1 && (uint32_t)(g1 >> 32) == want) { h1 = g1; d1 = true; }
          if (__all(d0 && d1)) break;
        }
      }
      hv0 = h0; hv1 = h1;
    }
    hl[wv * 128 + lane] = (uint32_t)hv0;
    hl[wv * 128 + 64 + lane] = (uint32_t)hv1;
    __syncthreads();  // barrier A
    // -- matvec: 64 dot2 from VGPR weights, h via 4 contiguous b128 reads --
    float a0 = 0.f, a1 = 0.f, a2 = 0.f, a3 = 0.f;
#pragma unroll
    for (int m = 0; m < 4; ++m) {
      const uint4 q = *(const uint4*)&hl[256 * m + 4 * lane];
      a0 = dot2f(wr[m][0][0], q.x, a0);
      a1 = dot2f(wr[m][0][1], q.x, a1);
      a2 = dot2f(wr[m][0][2], q.x, a2);
      a3 = dot2f(wr[m][0][3], q.x, a3);
      a0 = dot2f(wr[m][1][0], q.y, a0);
      a1 = dot2f(wr[m][1][1], q.y, a1);
      a2 = dot2f(wr[m][1][2], q.y, a2);
      a3 = dot2f(wr[m][1][3], q.y, a3);
      a0 = dot2f(wr[m][2][0], q.z, a0);
      a1 = dot2f(wr[m][2][1], q.z, a1);
      a2 = dot2f(wr[m][2][2], q.z, a2);
      a3 = dot2f(wr[m][2][3], q.z, a3);
      a0 = dot2f(wr[m][3][0], q.w, a0);
      a1 = dot2f(wr[m][3][1], q.w, a1);
      a2 = dot2f(wr[m][3][2], q.w, a2);
      a3 = dot2f(wr[m][3][3], q.w, a3);
    }
    a0 = wave_reduce_add(a0);
    a1 = wave_reduce_add(a1);
    a2 = wave_reduce_add(a2);
    a3 = wave_reduce_add(a3);
    if (lane == 63) {
      const float pF = a0 + wx[0] * xt + bb[0];
      const float pI = a1 + wx[1] * xt + bb[1];
      const float pU = a2 + wx[2] * xt + bb[2];
      const float pO = a3 + wx[3] * xt + bb[3];
      cell = fsig(pF) * cell + fsig(pI) * ftanh(pU);
      const float hval = fsig(pO) * ftanh(cell);
      const _Float16 hf = (_Float16)hval;
      hx16[wv] = __builtin_bit_cast(uint16_t, hf);
    }
    __syncthreads();  // barrier B
    if (tid < 4) {
      const uint32_t pk = smem[18432 + tid];  // {col 8b+2t, col 8b+2t+1} as 2xf16
      const unsigned long long val =
          (((unsigned long long)(uint32_t)(s + 1)) << 32) | (unsigned long long)pk;
      __hip_atomic_store(hbuf + (size_t)((s + 1) & 1) * NPAIR + blk * 4 + tid, val,
                         __ATOMIC_RELAXED, __HIP_MEMORY_SCOPE_AGENT);
      // owner-only hseq write: this block's 4 pairs of h(s), 16B/step
      hseq[(size_t)s * NPAIR + blk * 4 + tid] = pk;
    }
  }
#undef LDP
}

// ---------------- Phase C: wt pre-pack to f16 pairs ----------------
__global__ __launch_bounds__(256) void packwt_kernel(const float* __restrict__ wt,
                                                     uint32_t* __restrict__ wtp) {
  const int idx = blockIdx.x * 256 + threadIdx.x;
  const int p = idx >> 11;
  const int n = idx & 2047;
  wtp[idx] = packh2(wt[(size_t)(2 * p) * 2048 + n], wt[(size_t)(2 * p + 1) * 2048 + n]);
}

// ---------------- Phase D: logits GEMM (fdot2, 128x128 tile) ----------------
__global__ __launch_bounds__(256) void gemm_kernel(
    const uint32_t* __restrict__ A,  // [16384][1024] f16 pairs
    const uint32_t* __restrict__ B,  // [1024][2048] f16 pairs
    const float* __restrict__ bias, float* __restrict__ C) {
  __shared__ __align__(16) uint32_t As[16 * 132];
  __shared__ __align__(16) uint32_t Bs[16 * 132];
  const int tid = threadIdx.x;
  const int bx = blockIdx.x;
  const int m0 = (bx >> 4) * 128;
  const int n0 = (bx & 15) * 128;
  const int tm = (tid & 15) * 8;
  const int tn = (tid >> 4) * 8;
  float acc[8][8];
#pragma unroll
  for (int i = 0; i < 8; ++i)
#pragma unroll
    for (int j = 0; j < 8; ++j) acc[i][j] = 0.f;
  for (int kt = 0; kt < 64; ++kt) {
    const int p0 = kt * 16;
    __syncthreads();
#pragma unroll
    for (int r = 0; r < 8; ++r) {
      int idx = r * 256 + tid;
      int m = idx >> 4, pp = idx & 15;
      As[pp * 132 + m] = A[(size_t)(m0 + m) * 1024 + p0 + pp];
    }
#pragma unroll
    for (int r = 0; r < 8; ++r) {
      int idx = r * 256 + tid;
      int pp = idx >> 7, n = idx & 127;
      Bs[pp * 132 + n] = B[(size_t)(p0 + pp) * 2048 + n0 + n];
    }
    __syncthreads();
#pragma unroll
    for (int pp = 0; pp < 16; ++pp) {
      const uint4* ap = (const uint4*)(As + pp * 132 + tm);
      const uint4* bp = (const uint4*)(Bs + pp * 132 + tn);
      uint4 a0 = ap[0], a1 = ap[1];
      uint4 b0 = bp[0], b1 = bp[1];
      uint32_t av[8] = {a0.x, a0.y, a0.z, a0.w, a1.x, a1.y, a1.z, a1.w};
      uint32_t bv[8] = {b0.x, b0.y, b0.z, b0.w, b1.x, b1.y, b1.z, b1.w};
#pragma unroll
      for (int i = 0; i < 8; ++i)
#pragma unroll
        for (int j = 0; j < 8; ++j) acc[i][j] = dot2f(av[i], bv[j], acc[i][j]);
    }
  }
#pragma unroll
  for (int i = 0; i < 8; ++i) {
    const int m = m0 + tm + i;
    float4 o0, o1;
    o0.x = acc[i][0] + bias[n0 + tn + 0];
    o0.y = acc[i][1] + bias[n0 + tn + 1];
    o0.z = acc[i][2] + bias[n0 + tn + 2];
    o0.w = acc[i][3] + bias[n0 + tn + 3];
    o1.x = acc[i][4] + bias[n0 + tn + 4];
    o1.y = acc[i][5] + bias[n0 + tn + 5];
    o1.z = acc[i][6] + bias[n0 + tn + 6];
    o1.w = acc[i][7] + bias[n0 + tn + 7];
    *(float4*)(C + (size_t)m * 2048 + n0 + tn) = o0;
    *(float4*)(C + (size_t)m * 2048 + n0 + tn + 4) = o1;
  }
}

// ---------------- Phase E: row-wise log_softmax in place ----------------
__global__ __launch_bounds__(256) void lsm_kernel(float* __restrict__ C) {
  __shared__ float red[8];
  const int row = blockIdx.x;
  float* p = C + (size_t)row * HID;
  const int tid = threadIdx.x, lane = tid & 63, wv = tid >> 6;
  float v[8];
  float4 q0 = *(const float4*)(p + tid * 8);
  float4 q1 = *(const float4*)(p + tid * 8 + 4);
  v[0] = q0.x; v[1] = q0.y; v[2] = q0.z; v[3] = q0.w;
  v[4] = q1.x; v[5] = q1.y; v[6] = q1.z; v[7] = q1.w;
  float mx = v[0];
#pragma unroll
  for (int i = 1; i < 8; ++i) mx = fmaxf(mx, v[i]);
#pragma unroll
  for (int m = 32; m >= 1; m >>= 1) mx = fmaxf(mx, __shfl_xor(mx, m, 64));
  if (lane == 0) red[wv] = mx;
  __syncthreads();
  mx = fmaxf(fmaxf(red[0], red[1]), fmaxf(red[2], red[3]));
  float sm = 0.f;
#pragma unroll
  for (int i = 0; i < 8; ++i) {
    v[i] -= mx;
    sm += __expf(v[i]);
  }
#pragma unroll
  for (int m = 32; m >= 1; m >>= 1) sm += __shfl_xor(sm, m, 64);
  if (lane == 0) red[4 + wv] = sm;
  __syncthreads();
  sm = red[4] + red[5] + red[6] + red[7];
  const float ls = __logf(sm);
#pragma unroll
  for (int i = 0; i < 8; ++i) v[i] -= ls;
  q0.x = v[0]; q0.y = v[1]; q0.z = v[2]; q0.w = v[3];
  q1.x = v[4]; q1.y = v[5]; q1.z = v[6]; q1.w = v[7];
  *(float4*)(p + tid * 8) = q0;
  *(float4*)(p + tid * 8 + 4) = q1;
}

extern "C" void kernel_launch(void* const* d_in, const int* in_sizes, int n_in,
                              void* d_out, int out_size, void* d_ws, size_t ws_size,
                              hipStream_t stream) {
  const float* sent = (const float*)d_in[0];
  const float* fm_w = (const float*)d_in[1];
  const float* fm_b = (const float*)d_in[2];
  const float* c1w = (const float*)d_in[3];
  const float* c1b = (const float*)d_in[4];
  const float* p1w = (const float*)d_in[5];
  const float* p1b = (const float*)d_in[6];
  const float* c2w = (const float*)d_in[7];
  const float* c2b = (const float*)d_in[8];
  const float* p2w = (const float*)d_in[9];
  const float* p2b = (const float*)d_in[10];
  const float* c3w = (const float*)d_in[11];
  const float* c3b = (const float*)d_in[12];
  const float* hw = (const float*)d_in[13];
  const float* hb = (const float*)d_in[14];
  const float* wf = (const float*)d_in[15];
  const float* bf = (const float*)d_in[16];
  const float* wi = (const float*)d_in[17];
  const float* bi = (const float*)d_in[18];
  const float* wu = (const float*)d_in[19];
  const float* bu = (const float*)d_in[20];
  const float* wo = (const float*)d_in[21];
  const float* bo = (const float*)d_in[22];
  const float* wt = (const float*)d_in[23];
  const float* bt = (const float*)d_in[24];

  char* ws = (char*)d_ws;
  float* seq = (float*)ws;                                       // 64KB
  unsigned long long* hbuf = (unsigned long long*)(ws + 65536);  // 16KB (2 x 1024 u64)
  unsigned long long* lbuf = (unsigned long long*)(ws + 131072); // 128KB (8 x 2 x 1024 u64)
  uint32_t* hseq = (uint32_t*)(ws + 262144);                     // 64MB (pairs [S][1024])
  uint32_t* wtp = (uint32_t*)(ws + 262144 + (size_t)S_LEN * NPAIR * 4);  // 8MB
  float* C = (float*)d_out;

  qcnn_kernel<<<64, 256, 0, stream>>>(sent, fm_w, fm_b, c1w, c1b, p1w, p1b, c2w, c2b,
                                      p2w, p2b, c3w, c3b, hw, hb, seq, hbuf, lbuf);
  packwt_kernel<<<8192, 256, 0, stream>>>(wt, wtp);

  void* args[] = {(void*)&seq, (void*)&wf, (void*)&bf, (void*)&wi, (void*)&bi,
                  (void*)&wu, (void*)&bu, (void*)&wo, (void*)&bo,
                  (void*)&hbuf, (void*)&lbuf, (void*)&hseq};
  hipError_t rc = hipLaunchCooperativeKernel((void*)lstm_kernel, dim3(256), dim3(512),
                                             args, 0, stream);
  if (rc != hipSuccess) {
    // 128KB LDS forces 1 block/CU; grid == 256 == #CUs, so all blocks
    // are co-resident even under a plain launch.
    lstm_kernel<<<256, 512, 0, stream>>>(seq, wf, bf, wi, bi, wu, bu, wo, bo,
                                         hbuf, lbuf, hseq);
  }

  gemm_kernel<<<2048, 256, 0, stream>>>(hseq, wtp, bt, C);
  lsm_kernel<<<16384, 256, 0, stream>>>(C);
}

// Round 12
// 46469.321 us; speedup vs baseline: 1.1708x; 1.1708x over previous
//
#include <hip/hip_runtime.h>
#include <stdint.h>

#define S_LEN 16384
#define HID 2048
#define NPAIR 1024   // h pairs (2048/2)
#define NGRP 8       // XCD groups (blk % 8 under round-robin dispatch)

typedef _Float16 h2v __attribute__((ext_vector_type(2)));

__device__ __forceinline__ float dot2f(uint32_t a, uint32_t b, float c) {
#if __has_builtin(__builtin_amdgcn_fdot2)
  return __builtin_amdgcn_fdot2(__builtin_bit_cast(h2v, a), __builtin_bit_cast(h2v, b), c, false);
#else
  h2v ha = __builtin_bit_cast(h2v, a), hb = __builtin_bit_cast(h2v, b);
  return c + (float)ha[0] * (float)hb[0] + (float)ha[1] * (float)hb[1];
#endif
}

__device__ __forceinline__ uint32_t packh2(float a, float b) {
  h2v h; h[0] = (_Float16)a; h[1] = (_Float16)b;
  return __builtin_bit_cast(uint32_t, h);
}

__device__ __forceinline__ float fsig(float x) { return 1.0f / (1.0f + __expf(-x)); }
__device__ __forceinline__ float ftanh(float x) { return 2.0f / (1.0f + __expf(-2.0f * x)) - 1.0f; }

// L2-scope (sc0-only) ops: bypass L1, served by the XCD's L2, never forced to
// MALL. Used for intra-XCD relay->consumer fanout. If producer and consumer
// are NOT on the same XCD these may never show fresh data — every wait loop
// has an agent-scope fallback / escape, so correctness holds regardless.
__device__ __forceinline__ unsigned long long ld_l2(const unsigned long long* p) {
  unsigned long long v;
  asm volatile("global_load_dwordx2 %0, %1, off sc0\n\ts_waitcnt vmcnt(0)"
               : "=v"(v) : "v"(p) : "memory");
  return v;
}
__device__ __forceinline__ void st_l2(unsigned long long* p, unsigned long long v) {
  asm volatile("global_store_dwordx2 %0, %1, off sc0" : : "v"(p), "v"(v) : "memory");
}
__device__ __forceinline__ uint32_t ld_l2_u32(const uint32_t* p) {
  uint32_t v;
  asm volatile("global_load_dword %0, %1, off sc0\n\ts_waitcnt vmcnt(0)"
               : "=v"(v) : "v"(p) : "memory");
  return v;
}
__device__ __forceinline__ void st_l2_u32(uint32_t* p, uint32_t v) {
  asm volatile("global_store_dword %0, %1, off sc0" : : "v"(p), "v"(v) : "memory");
}

// Wave64 sum via DPP (VALU pipe only, no DS ops). Valid result in lane 63.
__device__ __forceinline__ float wave_reduce_add(float x) {
#define DPP_STEP(ctrl)                                                                   \
  {                                                                                      \
    int t_ = __builtin_amdgcn_update_dpp(0, __builtin_bit_cast(int, x), ctrl, 0xf, 0xf, true); \
    x += __builtin_bit_cast(float, t_);                                                  \
  }
  DPP_STEP(0x111)  // row_shr:1
  DPP_STEP(0x112)  // row_shr:2
  DPP_STEP(0x114)  // row_shr:4
  DPP_STEP(0x118)  // row_shr:8
  DPP_STEP(0x142)  // row_bcast:15
  DPP_STEP(0x143)  // row_bcast:31
#undef DPP_STEP
  return x;
}

// ---------------- Phase A: QCNN MLP per token + hbuf/lbuf/fbuf init ----------------
__global__ __launch_bounds__(256) void qcnn_kernel(
    const float* __restrict__ sent,
    const float* __restrict__ fm_w, const float* __restrict__ fm_b,
    const float* __restrict__ c1w, const float* __restrict__ c1b,
    const float* __restrict__ p1w, const float* __restrict__ p1b,
    const float* __restrict__ c2w, const float* __restrict__ c2b,
    const float* __restrict__ p2w, const float* __restrict__ p2b,
    const float* __restrict__ c3w, const float* __restrict__ c3b,
    const float* __restrict__ hw, const float* __restrict__ hb,
    float* __restrict__ seq, unsigned long long* __restrict__ hbuf,
    unsigned long long* __restrict__ lbuf, uint32_t* __restrict__ fbuf) {
  __shared__ float w[720];
  const int tid = threadIdx.x;
  const float* srcs[14] = {fm_w, fm_b, c1w, c1b, p1w, p1b, c2w, c2b, p2w, p2b, c3w, c3b, hw, hb};
  const int offs[14] = {0, 128, 144, 400, 416, 608, 620, 668, 672, 688, 692, 708, 712, 716};
  const int cnts[14] = {128, 16, 256, 16, 192, 12, 48, 4, 16, 4, 16, 4, 4, 1};
  for (int a = 0; a < 14; ++a)
    for (int i = tid; i < cnts[a]; i += 256) w[offs[a] + i] = srcs[a][i];
  if (blockIdx.x == 0) {
    // slot = u64: (tag32 << 32) | f16x2 pair. step s consumes tag s.
    // parity0 (even steps): tag 0, h(-1)=0; parity1: invalid tag.
    for (int p = tid; p < NPAIR; p += 256) {
      hbuf[p] = 0ull;
      hbuf[NPAIR + p] = 0x7FFFFFFFull << 32;
    }
    for (int idx = tid; idx < NGRP * NPAIR; idx += 256) {
      const int g = idx >> 10, i = idx & (NPAIR - 1);
      lbuf[(size_t)(g * 2) * NPAIR + i] = 0ull;
      lbuf[(size_t)(g * 2 + 1) * NPAIR + i] = 0x7FFFFFFFull << 32;
    }
    // flags: fbuf[((g*2+slot)*4+rep)*32]; slot bit = (idx>>7)&1.
    // parity0: value 0 (== want at s=0); parity1: invalid.
    for (int idx = tid; idx < NGRP * 2 * 4 * 32; idx += 256)
      fbuf[idx] = ((idx >> 7) & 1) ? 0xFFFFFFFFu : 0u;
  }
  __syncthreads();
  const int t = blockIdx.x * 256 + tid;
  float x[8];
#pragma unroll
  for (int i = 0; i < 8; ++i) x[i] = sent[t * 8 + i];
  float a0[16], a1[16], a2[12], a3[4], a4[4], a5[4];
#pragma unroll
  for (int o = 0; o < 16; ++o) {
    float s = w[128 + o];
#pragma unroll
    for (int i = 0; i < 8; ++i) s += x[i] * w[i * 16 + o];
    a0[o] = ftanh(s);
  }
#pragma unroll
  for (int o = 0; o < 16; ++o) {
    float s = w[400 + o];
#pragma unroll
    for (int i = 0; i < 16; ++i) s += a0[i] * w[144 + i * 16 + o];
    a1[o] = ftanh(s);
  }
#pragma unroll
  for (int o = 0; o < 12; ++o) {
    float s = w[608 + o];
#pragma unroll
    for (int i = 0; i < 16; ++i) s += a1[i] * w[416 + i * 12 + o];
    a2[o] = ftanh(s);
  }
#pragma unroll
  for (int o = 0; o < 4; ++o) {
    float s = w[668 + o];
#pragma unroll
    for (int i = 0; i < 12; ++i) s += a2[i] * w[620 + i * 4 + o];
    a3[o] = ftanh(s);
  }
#pragma unroll
  for (int o = 0; o < 4; ++o) {
    float s = w[688 + o];
#pragma unroll
    for (int i = 0; i < 4; ++i) s += a3[i] * w[672 + i * 4 + o];
    a4[o] = ftanh(s);
  }
#pragma unroll
  for (int o = 0; o < 4; ++o) {
    float s = w[708 + o];
#pragma unroll
    for (int i = 0; i < 4; ++i) s += a4[i] * w[692 + i * 4 + o];
    a5[o] = ftanh(s);
  }
  float s = w[716];
#pragma unroll
  for (int i = 0; i < 4; ++i) s += a5[i] * w[712 + i];
  seq[t] = fsig(s);
}

// ---------------- Phase B: persistent LSTM scan (XCD relay + flag broadcast) ----------------
// 256 blocks x 512 threads (8 waves). Wave wv owns hidden unit col = blk*8+wv.
// Weights in VGPRs. Group g = blk & 7 (round-robin => same XCD). Blocks 0..7
// are relays: sleep-paced agent-scope poll of global hbuf -> sc0 fanout into
// lbuf[g][parity] -> (after barrier A's vmcnt drain) tid<4 store 4 replicated
// per-group FLAG lines (sc0). Consumers sleep-pace-poll ONE flag line (all 8
// waves on the same value -> detect spread collapses), then run the r10 data
// poll which succeeds on its first local round. Flag wait is capped; the data
// poll keeps its agent-scope fallback -> placement-independent correctness.
__global__ __launch_bounds__(512, 2) void lstm_kernel(
    const float* __restrict__ seq,
    const float* __restrict__ wfp, const float* __restrict__ bfp,
    const float* __restrict__ wip, const float* __restrict__ bip,
    const float* __restrict__ wup, const float* __restrict__ bup,
    const float* __restrict__ wop, const float* __restrict__ bop,
    unsigned long long* __restrict__ hbuf,
    unsigned long long* __restrict__ lbuf,
    uint32_t* __restrict__ fbuf,
    uint32_t* __restrict__ hseq) {
  __shared__ __align__(16) uint32_t smem[32768];  // 128 KB
  const int tid = threadIdx.x;
  const int lane = tid & 63;
  const int wv = tid >> 6;  // 0..7
  const int blk = blockIdx.x;
  const int grp = blk & (NGRP - 1);
  const bool is_relay = (blk < NGRP);
  const int col = blk * 8 + wv;
  const float* wptr[4] = {wfp, wip, wup, wop};
  const float* bptr[4] = {bfp, bip, bup, bop};

  // ---- stage packed-f16 weights into LDS (temporary) ----
  {
    const int jj = tid & 7;
    const int sc = blk * 8 + jj;
    const int pb = tid >> 3;  // 0..63
#pragma unroll
    for (int g = 0; g < 4; ++g) {
      const float* wsp = wptr[g];
      for (int pp = 0; pp < 16; ++pp) {
        int p = pp * 64 + pb;
        float w0 = wsp[(size_t)(1 + 2 * p) * HID + sc];
        float w1 = wsp[(size_t)(2 + 2 * p) * HID + sc];
        smem[(jj * 1024 + p) * 4 + g] = packh2(w0, w1);
      }
    }
  }
  __syncthreads();
  // ---- LDS -> VGPRs: wr[m][j][g] = gate-g weight pair (256m + 4*lane + j) ----
  uint32_t wr[4][4][4];
#pragma unroll
  for (int m = 0; m < 4; ++m)
#pragma unroll
    for (int j = 0; j < 4; ++j) {
      const uint4 q = *(const uint4*)&smem[(wv * 1024 + 256 * m + 4 * lane + j) * 4];
      wr[m][j][0] = q.x; wr[m][j][1] = q.y; wr[m][j][2] = q.z; wr[m][j][3] = q.w;
    }
  float wx[4], bb[4];
#pragma unroll
  for (int g = 0; g < 4; ++g) {
    wx[g] = wptr[g][col];  // row 0 = x coefficient
    bb[g] = bptr[g][col];
  }
  __syncthreads();
  // ---- repurpose LDS: [0,64K) = seq, [64K,72K) = h pair double buffer, then hx ----
  float* seqf = (float*)smem;
  for (int i = tid; i < 4096; i += 512) ((float4*)seqf)[i] = ((const float4*)seq)[i];
  uint32_t* hlds = smem + 16384;                   // 2 x 1024 u32 pairs
  uint16_t* hx16 = (uint16_t*)(smem + 18432);      // 8 x u16
  __syncthreads();

#define LDP(p) __hip_atomic_load((p), __ATOMIC_RELAXED, __HIP_MEMORY_SCOPE_AGENT)

  const int frep = (blk >> 3) & 3;
  float cell = 0.f;
  for (int s = 0; s < S_LEN; ++s) {
    const int slot = s & 1;
    uint32_t* hl = hlds + slot * NPAIR;
    const float xt = seqf[s];
    const uint32_t want = (uint32_t)s;
    unsigned long long hv0, hv1;
    if (is_relay) {
      // -- relay: sleep-paced global poll of my 128-pair window (champion r10) --
      unsigned long long* src = hbuf + (size_t)slot * NPAIR + wv * 128 + lane;
      unsigned long long h0 = LDP(src), h1 = LDP(src + 64);
      while (true) {
        const bool ok0 = ((uint32_t)(h0 >> 32) == want);
        const bool ok1 = ((uint32_t)(h1 >> 32) == want);
        if (__all(ok0 && ok1)) break;
        __builtin_amdgcn_s_sleep(1);
        if (!ok0) h0 = LDP(src);
        if (!ok1) h1 = LDP(src + 64);
      }
      // -- fan out into this XCD's local buffer (L2-resident, fire-and-forget) --
      unsigned long long* ldst = lbuf + (size_t)(grp * 2 + slot) * NPAIR + wv * 128 + lane;
      st_l2(ldst, h0);
      st_l2(ldst + 64, h1);
      hv0 = h0; hv1 = h1;
    } else {
      // -- consumer: sleep-paced FLAG wait (capped), then r10 data poll --
      const uint32_t* fptr = fbuf + ((grp * 2 + slot) * 4 + frep) * 32;
      for (int fi = 0; fi < 6; ++fi) {
        if (ld_l2_u32(fptr) == want) break;
        __builtin_amdgcn_s_sleep(1);
      }
      const unsigned long long* lsrc =
          lbuf + (size_t)(grp * 2 + slot) * NPAIR + wv * 128 + lane;
      unsigned long long* gsrc = hbuf + (size_t)slot * NPAIR + wv * 128 + lane;
      bool d0 = false, d1 = false;
      unsigned long long h0 = 0, h1 = 0;
      while (true) {
#pragma unroll
        for (int r = 0; r < 2; ++r) {
          if (!d0) { unsigned long long t = ld_l2(lsrc);      if ((uint32_t)(t >> 32) == want) { h0 = t; d0 = true; } }
          if (!d1) { unsigned long long t = ld_l2(lsrc + 64); if ((uint32_t)(t >> 32) == want) { h1 = t; d1 = true; } }
          if (__all(d0 && d1)) goto got;
        }
        if (!d0) { unsigned long long t = LDP(gsrc);      if ((uint32_t)(t >> 32) == want) { h0 = t; d0 = true; } }
        if (!d1) { unsigned long long t = LDP(gsrc + 64); if ((uint32_t)(t >> 32) == want) { h1 = t; d1 = true; } }
        if (__all(d0 && d1)) break;
        __builtin_amdgcn_s_sleep(1);
      }
got:
      hv0 = h0; hv1 = h1;
    }
    hl[wv * 128 + lane] = (uint32_t)hv0;
    hl[wv * 128 + 64 + lane] = (uint32_t)hv1;
    __syncthreads();  // barrier A (drains vmcnt -> relay fanout visible in L2)
    if (is_relay && tid < 4) {
      // flag AFTER the drain: data is guaranteed in L2 before any consumer
      // can see the flag. 4 replicated lines to spread read pressure.
      st_l2_u32(fbuf + ((grp * 2 + slot) * 4 + tid) * 32, want);
    }
    // -- matvec: 64 dot2 from VGPR weights, h via 4 contiguous b128 reads --
    float a0 = 0.f, a1 = 0.f, a2 = 0.f, a3 = 0.f;
#pragma unroll
    for (int m = 0; m < 4; ++m) {
      const uint4 q = *(const uint4*)&hl[256 * m + 4 * lane];
      a0 = dot2f(wr[m][0][0], q.x, a0);
      a1 = dot2f(wr[m][0][1], q.x, a1);
      a2 = dot2f(wr[m][0][2], q.x, a2);
      a3 = dot2f(wr[m][0][3], q.x, a3);
      a0 = dot2f(wr[m][1][0], q.y, a0);
      a1 = dot2f(wr[m][1][1], q.y, a1);
      a2 = dot2f(wr[m][1][2], q.y, a2);
      a3 = dot2f(wr[m][1][3], q.y, a3);
      a0 = dot2f(wr[m][2][0], q.z, a0);
      a1 = dot2f(wr[m][2][1], q.z, a1);
      a2 = dot2f(wr[m][2][2], q.z, a2);
      a3 = dot2f(wr[m][2][3], q.z, a3);
      a0 = dot2f(wr[m][3][0], q.w, a0);
      a1 = dot2f(wr[m][3][1], q.w, a1);
      a2 = dot2f(wr[m][3][2], q.w, a2);
      a3 = dot2f(wr[m][3][3], q.w, a3);
    }
    a0 = wave_reduce_add(a0);
    a1 = wave_reduce_add(a1);
    a2 = wave_reduce_add(a2);
    a3 = wave_reduce_add(a3);
    if (lane == 63) {
      const float pF = a0 + wx[0] * xt + bb[0];
      const float pI = a1 + wx[1] * xt + bb[1];
      const float pU = a2 + wx[2] * xt + bb[2];
      const float pO = a3 + wx[3] * xt + bb[3];
      cell = fsig(pF) * cell + fsig(pI) * ftanh(pU);
      const float hval = fsig(pO) * ftanh(cell);
      const _Float16 hf = (_Float16)hval;
      hx16[wv] = __builtin_bit_cast(uint16_t, hf);
    }
    __syncthreads();  // barrier B
    if (tid < 4) {
      const uint32_t pk = smem[18432 + tid];  // {col 8b+2t, col 8b+2t+1} as 2xf16
      const unsigned long long val =
          (((unsigned long long)(uint32_t)(s + 1)) << 32) | (unsigned long long)pk;
      __hip_atomic_store(hbuf + (size_t)((s + 1) & 1) * NPAIR + blk * 4 + tid, val,
                         __ATOMIC_RELAXED, __HIP_MEMORY_SCOPE_AGENT);
      // owner-only hseq write: this block's 4 pairs of h(s), 16B/step
      hseq[(size_t)s * NPAIR + blk * 4 + tid] = pk;
    }
  }
#undef LDP
}

// ---------------- Phase C: wt pre-pack to f16 pairs ----------------
__global__ __launch_bounds__(256) void packwt_kernel(const float* __restrict__ wt,
                                                     uint32_t* __restrict__ wtp) {
  const int idx = blockIdx.x * 256 + threadIdx.x;
  const int p = idx >> 11;
  const int n = idx & 2047;
  wtp[idx] = packh2(wt[(size_t)(2 * p) * 2048 + n], wt[(size_t)(2 * p + 1) * 2048 + n]);
}

// ---------------- Phase D: logits GEMM (fdot2, 128x128 tile) ----------------
__global__ __launch_bounds__(256) void gemm_kernel(
    const uint32_t* __restrict__ A,  // [16384][1024] f16 pairs
    const uint32_t* __restrict__ B,  // [1024][2048] f16 pairs
    const float* __restrict__ bias, float* __restrict__ C) {
  __shared__ __align__(16) uint32_t As[16 * 132];
  __shared__ __align__(16) uint32_t Bs[16 * 132];
  const int tid = threadIdx.x;
  const int bx = blockIdx.x;
  const int m0 = (bx >> 4) * 128;
  const int n0 = (bx & 15) * 128;
  const int tm = (tid & 15) * 8;
  const int tn = (tid >> 4) * 8;
  float acc[8][8];
#pragma unroll
  for (int i = 0; i < 8; ++i)
#pragma unroll
    for (int j = 0; j < 8; ++j) acc[i][j] = 0.f;
  for (int kt = 0; kt < 64; ++kt) {
    const int p0 = kt * 16;
    __syncthreads();
#pragma unroll
    for (int r = 0; r < 8; ++r) {
      int idx = r * 256 + tid;
      int m = idx >> 4, pp = idx & 15;
      As[pp * 132 + m] = A[(size_t)(m0 + m) * 1024 + p0 + pp];
    }
#pragma unroll
    for (int r = 0; r < 8; ++r) {
      int idx = r * 256 + tid;
      int pp = idx >> 7, n = idx & 127;
      Bs[pp * 132 + n] = B[(size_t)(p0 + pp) * 2048 + n0 + n];
    }
    __syncthreads();
#pragma unroll
    for (int pp = 0; pp < 16; ++pp) {
      const uint4* ap = (const uint4*)(As + pp * 132 + tm);
      const uint4* bp = (const uint4*)(Bs + pp * 132 + tn);
      uint4 a0 = ap[0], a1 = ap[1];
      uint4 b0 = bp[0], b1 = bp[1];
      uint32_t av[8] = {a0.x, a0.y, a0.z, a0.w, a1.x, a1.y, a1.z, a1.w};
      uint32_t bv[8] = {b0.x, b0.y, b0.z, b0.w, b1.x, b1.y, b1.z, b1.w};
#pragma unroll
      for (int i = 0; i < 8; ++i)
#pragma unroll
        for (int j = 0; j < 8; ++j) acc[i][j] = dot2f(av[i], bv[j], acc[i][j]);
    }
  }
#pragma unroll
  for (int i = 0; i < 8; ++i) {
    const int m = m0 + tm + i;
    float4 o0, o1;
    o0.x = acc[i][0] + bias[n0 + tn + 0];
    o0.y = acc[i][1] + bias[n0 + tn + 1];
    o0.z = acc[i][2] + bias[n0 + tn + 2];
    o0.w = acc[i][3] + bias[n0 + tn + 3];
    o1.x = acc[i][4] + bias[n0 + tn + 4];
    o1.y = acc[i][5] + bias[n0 + tn + 5];
    o1.z = acc[i][6] + bias[n0 + tn + 6];
    o1.w = acc[i][7] + bias[n0 + tn + 7];
    *(float4*)(C + (size_t)m * 2048 + n0 + tn) = o0;
    *(float4*)(C + (size_t)m * 2048 + n0 + tn + 4) = o1;
  }
}

// ---------------- Phase E: row-wise log_softmax in place ----------------
__global__ __launch_bounds__(256) void lsm_kernel(float* __restrict__ C) {
  __shared__ float red[8];
  const int row = blockIdx.x;
  float* p = C + (size_t)row * HID;
  const int tid = threadIdx.x, lane = tid & 63, wv = tid >> 6;
  float v[8];
  float4 q0 = *(const float4*)(p + tid * 8);
  float4 q1 = *(const float4*)(p + tid * 8 + 4);
  v[0] = q0.x; v[1] = q0.y; v[2] = q0.z; v[3] = q0.w;
  v[4] = q1.x; v[5] = q1.y; v[6] = q1.z; v[7] = q1.w;
  float mx = v[0];
#pragma unroll
  for (int i = 1; i < 8; ++i) mx = fmaxf(mx, v[i]);
#pragma unroll
  for (int m = 32; m >= 1; m >>= 1) mx = fmaxf(mx, __shfl_xor(mx, m, 64));
  if (lane == 0) red[wv] = mx;
  __syncthreads();
  mx = fmaxf(fmaxf(red[0], red[1]), fmaxf(red[2], red[3]));
  float sm = 0.f;
#pragma unroll
  for (int i = 0; i < 8; ++i) {
    v[i] -= mx;
    sm += __expf(v[i]);
  }
#pragma unroll
  for (int m = 32; m >= 1; m >>= 1) sm += __shfl_xor(sm, m, 64);
  if (lane == 0) red[4 + wv] = sm;
  __syncthreads();
  sm = red[4] + red[5] + red[6] + red[7];
  const float ls = __logf(sm);
#pragma unroll
  for (int i = 0; i < 8; ++i) v[i] -= ls;
  q0.x = v[0]; q0.y = v[1]; q0.z = v[2]; q0.w = v[3];
  q1.x = v[4]; q1.y = v[5]; q1.z = v[6]; q1.w = v[7];
  *(float4*)(p + tid * 8) = q0;
  *(float4*)(p + tid * 8 + 4) = q1;
}

extern "C" void kernel_launch(void* const* d_in, const int* in_sizes, int n_in,
                              void* d_out, int out_size, void* d_ws, size_t ws_size,
                              hipStream_t stream) {
  const float* sent = (const float*)d_in[0];
  const float* fm_w = (const float*)d_in[1];
  const float* fm_b = (const float*)d_in[2];
  const float* c1w = (const float*)d_in[3];
  const float* c1b = (const float*)d_in[4];
  const float* p1w = (const float*)d_in[5];
  const float* p1b = (const float*)d_in[6];
  const float* c2w = (const float*)d_in[7];
  const float* c2b = (const float*)d_in[8];
  const float* p2w = (const float*)d_in[9];
  const float* p2b = (const float*)d_in[10];
  const float* c3w = (const float*)d_in[11];
  const float* c3b = (const float*)d_in[12];
  const float* hw = (const float*)d_in[13];
  const float* hb = (const float*)d_in[14];
  const float* wf = (const float*)d_in[15];
  const float* bf = (const float*)d_in[16];
  const float* wi = (const float*)d_in[17];
  const float* bi = (const float*)d_in[18];
  const float* wu = (const float*)d_in[19];
  const float* bu = (const float*)d_in[20];
  const float* wo = (const float*)d_in[21];
  const float* bo = (const float*)d_in[22];
  const float* wt = (const float*)d_in[23];
  const float* bt = (const float*)d_in[24];

  char* ws = (char*)d_ws;
  float* seq = (float*)ws;                                       // 64KB @ 0
  unsigned long long* hbuf = (unsigned long long*)(ws + 65536);  // 16KB (2 x 1024 u64)
  unsigned long long* lbuf = (unsigned long long*)(ws + 131072); // 128KB (8 x 2 x 1024 u64)
  uint32_t* fbuf = (uint32_t*)(ws + 262144);                     // 8KB flags (pad to 64KB)
  uint32_t* hseq = (uint32_t*)(ws + 327680);                     // 64MB (pairs [S][1024])
  uint32_t* wtp = (uint32_t*)(ws + 327680 + (size_t)S_LEN * NPAIR * 4);  // 8MB
  float* C = (float*)d_out;

  qcnn_kernel<<<64, 256, 0, stream>>>(sent, fm_w, fm_b, c1w, c1b, p1w, p1b, c2w, c2b,
                                      p2w, p2b, c3w, c3b, hw, hb, seq, hbuf, lbuf, fbuf);
  packwt_kernel<<<8192, 256, 0, stream>>>(wt, wtp);

  void* args[] = {(void*)&seq, (void*)&wf, (void*)&bf, (void*)&wi, (void*)&bi,
                  (void*)&wu, (void*)&bu, (void*)&wo, (void*)&bo,
                  (void*)&hbuf, (void*)&lbuf, (void*)&fbuf, (void*)&hseq};
  hipError_t rc = hipLaunchCooperativeKernel((void*)lstm_kernel, dim3(256), dim3(512),
                                             args, 0, stream);
  if (rc != hipSuccess) {
    // 128KB LDS forces 1 block/CU; grid == 256 == #CUs, so all blocks
    // are co-resident even under a plain launch.
    lstm_kernel<<<256, 512, 0, stream>>>(seq, wf, bf, wi, bi, wu, bu, wo, bo,
                                         hbuf, lbuf, fbuf, hseq);
  }

  gemm_kernel<<<2048, 256, 0, stream>>>(hseq, wtp, bt, C);
  lsm_kernel<<<16384, 256, 0, stream>>>(C);
}

// Round 13
// 46238.757 us; speedup vs baseline: 1.1766x; 1.0050x over previous
//
#include <hip/hip_runtime.h>
#include <stdint.h>

#define S_LEN 16384
#define HID 2048
#define NPAIR 1024   // h pairs (2048/2)
#define NGRP 8       // XCD groups (blk % 8 under round-robin dispatch)

typedef _Float16 h2v __attribute__((ext_vector_type(2)));

__device__ __forceinline__ float dot2f(uint32_t a, uint32_t b, float c) {
#if __has_builtin(__builtin_amdgcn_fdot2)
  return __builtin_amdgcn_fdot2(__builtin_bit_cast(h2v, a), __builtin_bit_cast(h2v, b), c, false);
#else
  h2v ha = __builtin_bit_cast(h2v, a), hb = __builtin_bit_cast(h2v, b);
  return c + (float)ha[0] * (float)hb[0] + (float)ha[1] * (float)hb[1];
#endif
}

__device__ __forceinline__ uint32_t packh2(float a, float b) {
  h2v h; h[0] = (_Float16)a; h[1] = (_Float16)b;
  return __builtin_bit_cast(uint32_t, h);
}

__device__ __forceinline__ float fsig(float x) { return 1.0f / (1.0f + __expf(-x)); }
__device__ __forceinline__ float ftanh(float x) { return 2.0f / (1.0f + __expf(-2.0f * x)) - 1.0f; }

// L2-scope (sc0-only) ops: bypass L1, served by the XCD's L2, never forced to
// MALL. Used for intra-XCD relay->consumer fanout. If producer and consumer
// are NOT on the same XCD these may never show fresh data — the calling loop
// always has an agent-scope fallback, so correctness holds.
__device__ __forceinline__ void ld_l2_pair(const unsigned long long* p0,
                                           const unsigned long long* p1,
                                           unsigned long long& v0,
                                           unsigned long long& v1) {
  asm volatile("global_load_dwordx2 %0, %2, off sc0\n\t"
               "global_load_dwordx2 %1, %3, off sc0\n\t"
               "s_waitcnt vmcnt(0)"
               : "=&v"(v0), "=&v"(v1)
               : "v"(p0), "v"(p1)
               : "memory");
}
__device__ __forceinline__ void st_l2(unsigned long long* p, unsigned long long v) {
  asm volatile("global_store_dwordx2 %0, %1, off sc0" : : "v"(p), "v"(v) : "memory");
}

// Wave64 sum via DPP (VALU pipe only, no DS ops). Valid result in lane 63.
__device__ __forceinline__ float wave_reduce_add(float x) {
#define DPP_STEP(ctrl)                                                                   \
  {                                                                                      \
    int t_ = __builtin_amdgcn_update_dpp(0, __builtin_bit_cast(int, x), ctrl, 0xf, 0xf, true); \
    x += __builtin_bit_cast(float, t_);                                                  \
  }
  DPP_STEP(0x111)  // row_shr:1
  DPP_STEP(0x112)  // row_shr:2
  DPP_STEP(0x114)  // row_shr:4
  DPP_STEP(0x118)  // row_shr:8
  DPP_STEP(0x142)  // row_bcast:15
  DPP_STEP(0x143)  // row_bcast:31
#undef DPP_STEP
  return x;
}

// ---------------- Phase A: QCNN MLP per token + hbuf/lbuf init ----------------
__global__ __launch_bounds__(256) void qcnn_kernel(
    const float* __restrict__ sent,
    const float* __restrict__ fm_w, const float* __restrict__ fm_b,
    const float* __restrict__ c1w, const float* __restrict__ c1b,
    const float* __restrict__ p1w, const float* __restrict__ p1b,
    const float* __restrict__ c2w, const float* __restrict__ c2b,
    const float* __restrict__ p2w, const float* __restrict__ p2b,
    const float* __restrict__ c3w, const float* __restrict__ c3b,
    const float* __restrict__ hw, const float* __restrict__ hb,
    float* __restrict__ seq, unsigned long long* __restrict__ hbuf,
    unsigned long long* __restrict__ lbuf) {
  __shared__ float w[720];
  const int tid = threadIdx.x;
  const float* srcs[14] = {fm_w, fm_b, c1w, c1b, p1w, p1b, c2w, c2b, p2w, p2b, c3w, c3b, hw, hb};
  const int offs[14] = {0, 128, 144, 400, 416, 608, 620, 668, 672, 688, 692, 708, 712, 716};
  const int cnts[14] = {128, 16, 256, 16, 192, 12, 48, 4, 16, 4, 16, 4, 4, 1};
  for (int a = 0; a < 14; ++a)
    for (int i = tid; i < cnts[a]; i += 256) w[offs[a] + i] = srcs[a][i];
  if (blockIdx.x == 0) {
    // slot = u64: (tag32 << 32) | f16x2 pair. step s consumes tag s.
    // parity0 (even steps): tag 0, h(-1)=0; parity1: invalid tag.
    for (int p = tid; p < NPAIR; p += 256) {
      hbuf[p] = 0ull;
      hbuf[NPAIR + p] = 0x7FFFFFFFull << 32;
    }
    for (int idx = tid; idx < NGRP * NPAIR; idx += 256) {
      const int g = idx >> 10, i = idx & (NPAIR - 1);
      lbuf[(size_t)(g * 2) * NPAIR + i] = 0ull;
      lbuf[(size_t)(g * 2 + 1) * NPAIR + i] = 0x7FFFFFFFull << 32;
    }
  }
  __syncthreads();
  const int t = blockIdx.x * 256 + tid;
  float x[8];
#pragma unroll
  for (int i = 0; i < 8; ++i) x[i] = sent[t * 8 + i];
  float a0[16], a1[16], a2[12], a3[4], a4[4], a5[4];
#pragma unroll
  for (int o = 0; o < 16; ++o) {
    float s = w[128 + o];
#pragma unroll
    for (int i = 0; i < 8; ++i) s += x[i] * w[i * 16 + o];
    a0[o] = ftanh(s);
  }
#pragma unroll
  for (int o = 0; o < 16; ++o) {
    float s = w[400 + o];
#pragma unroll
    for (int i = 0; i < 16; ++i) s += a0[i] * w[144 + i * 16 + o];
    a1[o] = ftanh(s);
  }
#pragma unroll
  for (int o = 0; o < 12; ++o) {
    float s = w[608 + o];
#pragma unroll
    for (int i = 0; i < 16; ++i) s += a1[i] * w[416 + i * 12 + o];
    a2[o] = ftanh(s);
  }
#pragma unroll
  for (int o = 0; o < 4; ++o) {
    float s = w[668 + o];
#pragma unroll
    for (int i = 0; i < 12; ++i) s += a2[i] * w[620 + i * 4 + o];
    a3[o] = ftanh(s);
  }
#pragma unroll
  for (int o = 0; o < 4; ++o) {
    float s = w[688 + o];
#pragma unroll
    for (int i = 0; i < 4; ++i) s += a3[i] * w[672 + i * 4 + o];
    a4[o] = ftanh(s);
  }
#pragma unroll
  for (int o = 0; o < 4; ++o) {
    float s = w[708 + o];
#pragma unroll
    for (int i = 0; i < 4; ++i) s += a4[i] * w[692 + i * 4 + o];
    a5[o] = ftanh(s);
  }
  float s = w[716];
#pragma unroll
  for (int i = 0; i < 4; ++i) s += a5[i] * w[712 + i];
  seq[t] = fsig(s);
}

// ---------------- Phase B: persistent LSTM scan (XCD relay broadcast) ----------------
// 256 blocks x 512 threads (8 waves). Wave wv owns hidden unit col = blk*8+wv.
// Weights in VGPRs. Group g = blk & 7 (round-robin => same XCD). Blocks 0..7
// are per-group relays: NO-SLEEP rotating 2-pair poll of global hbuf (64
// waves device-wide on MALL — r9 proved 2048 waves dense costs only ~1ms),
// then sc0 fanout into lbuf[g][parity]. Consumers poll lbuf with ONE
// single-waitcnt sc0 pair-load per iteration, s_sleep(1) retained (r11's
// killer was sleepless hammering starving relay writes), agent-scope
// fallback every 4th iteration (placement-independent correctness).
__global__ __launch_bounds__(512, 2) void lstm_kernel(
    const float* __restrict__ seq,
    const float* __restrict__ wfp, const float* __restrict__ bfp,
    const float* __restrict__ wip, const float* __restrict__ bip,
    const float* __restrict__ wup, const float* __restrict__ bup,
    const float* __restrict__ wop, const float* __restrict__ bop,
    unsigned long long* __restrict__ hbuf,
    unsigned long long* __restrict__ lbuf,
    uint32_t* __restrict__ hseq) {
  __shared__ __align__(16) uint32_t smem[32768];  // 128 KB
  const int tid = threadIdx.x;
  const int lane = tid & 63;
  const int wv = tid >> 6;  // 0..7
  const int blk = blockIdx.x;
  const int grp = blk & (NGRP - 1);
  const bool is_relay = (blk < NGRP);
  const int col = blk * 8 + wv;
  const float* wptr[4] = {wfp, wip, wup, wop};
  const float* bptr[4] = {bfp, bip, bup, bop};

  // ---- stage packed-f16 weights into LDS (temporary) ----
  {
    const int jj = tid & 7;
    const int sc = blk * 8 + jj;
    const int pb = tid >> 3;  // 0..63
#pragma unroll
    for (int g = 0; g < 4; ++g) {
      const float* wsp = wptr[g];
      for (int pp = 0; pp < 16; ++pp) {
        int p = pp * 64 + pb;
        float w0 = wsp[(size_t)(1 + 2 * p) * HID + sc];
        float w1 = wsp[(size_t)(2 + 2 * p) * HID + sc];
        smem[(jj * 1024 + p) * 4 + g] = packh2(w0, w1);
      }
    }
  }
  __syncthreads();
  // ---- LDS -> VGPRs: wr[m][j][g] = gate-g weight pair (256m + 4*lane + j) ----
  uint32_t wr[4][4][4];
#pragma unroll
  for (int m = 0; m < 4; ++m)
#pragma unroll
    for (int j = 0; j < 4; ++j) {
      const uint4 q = *(const uint4*)&smem[(wv * 1024 + 256 * m + 4 * lane + j) * 4];
      wr[m][j][0] = q.x; wr[m][j][1] = q.y; wr[m][j][2] = q.z; wr[m][j][3] = q.w;
    }
  float wx[4], bb[4];
#pragma unroll
  for (int g = 0; g < 4; ++g) {
    wx[g] = wptr[g][col];  // row 0 = x coefficient
    bb[g] = bptr[g][col];
  }
  __syncthreads();
  // ---- repurpose LDS: [0,64K) = seq, [64K,72K) = h pair double buffer, then hx ----
  float* seqf = (float*)smem;
  for (int i = tid; i < 4096; i += 512) ((float4*)seqf)[i] = ((const float4*)seq)[i];
  uint32_t* hlds = smem + 16384;                   // 2 x 1024 u32 pairs
  uint16_t* hx16 = (uint16_t*)(smem + 18432);      // 8 x u16
  __syncthreads();

#define LDP(p) __hip_atomic_load((p), __ATOMIC_RELAXED, __HIP_MEMORY_SCOPE_AGENT)

  float cell = 0.f;
  for (int s = 0; s < S_LEN; ++s) {
    const int slot = s & 1;
    uint32_t* hl = hlds + slot * NPAIR;
    const float xt = seqf[s];
    const uint32_t want = (uint32_t)s;
    unsigned long long hv0, hv1;
    if (is_relay) {
      // -- relay: NO-SLEEP rotating 2-pair poll of my global 128-pair window --
      unsigned long long* src = hbuf + (size_t)slot * NPAIR + wv * 128 + lane;
      unsigned long long A0 = LDP(src), A1 = LDP(src + 64);
      unsigned long long B0 = LDP(src), B1 = LDP(src + 64);
      while (true) {
        const bool okA = ((uint32_t)(A0 >> 32) == want) & ((uint32_t)(A1 >> 32) == want);
        if (__all(okA)) { hv0 = A0; hv1 = A1; break; }
        A0 = LDP(src); A1 = LDP(src + 64);
        const bool okB = ((uint32_t)(B0 >> 32) == want) & ((uint32_t)(B1 >> 32) == want);
        if (__all(okB)) { hv0 = B0; hv1 = B1; break; }
        B0 = LDP(src); B1 = LDP(src + 64);
      }
      // -- fan out into this XCD's local buffer (L2-resident, fire-and-forget) --
      unsigned long long* ldst = lbuf + (size_t)(grp * 2 + slot) * NPAIR + wv * 128 + lane;
      st_l2(ldst, hv0);
      st_l2(ldst + 64, hv1);
    } else {
      // -- consumer: one sc0 pair-load per iter (single waitcnt), sleep kept,
      //    agent-scope fallback every 4th iter --
      const unsigned long long* lsrc =
          lbuf + (size_t)(grp * 2 + slot) * NPAIR + wv * 128 + lane;
      unsigned long long* gsrc = hbuf + (size_t)slot * NPAIR + wv * 128 + lane;
      bool d0 = false, d1 = false;
      unsigned long long h0 = 0, h1 = 0;
      int it = 0;
      while (true) {
        unsigned long long t0, t1;
        ld_l2_pair(lsrc, lsrc + 64, t0, t1);
        if (!d0 && (uint32_t)(t0 >> 32) == want) { h0 = t0; d0 = true; }
        if (!d1 && (uint32_t)(t1 >> 32) == want) { h1 = t1; d1 = true; }
        if (__all(d0 && d1)) break;
        if ((++it & 3) == 0) {
          unsigned long long g0 = LDP(gsrc), g1 = LDP(gsrc + 64);
          if (!d0 && (uint32_t)(g0 >> 32) == want) { h0 = g0; d0 = true; }
          if (!d1 && (uint32_t)(g1 >> 32) == want) { h1 = g1; d1 = true; }
          if (__all(d0 && d1)) break;
        }
        __builtin_amdgcn_s_sleep(1);
      }
      hv0 = h0; hv1 = h1;
    }
    hl[wv * 128 + lane] = (uint32_t)hv0;
    hl[wv * 128 + 64 + lane] = (uint32_t)hv1;
    __syncthreads();  // barrier A
    // -- matvec: 64 dot2 from VGPR weights, h via 4 contiguous b128 reads --
    float a0 = 0.f, a1 = 0.f, a2 = 0.f, a3 = 0.f;
#pragma unroll
    for (int m = 0; m < 4; ++m) {
      const uint4 q = *(const uint4*)&hl[256 * m + 4 * lane];
      a0 = dot2f(wr[m][0][0], q.x, a0);
      a1 = dot2f(wr[m][0][1], q.x, a1);
      a2 = dot2f(wr[m][0][2], q.x, a2);
      a3 = dot2f(wr[m][0][3], q.x, a3);
      a0 = dot2f(wr[m][1][0], q.y, a0);
      a1 = dot2f(wr[m][1][1], q.y, a1);
      a2 = dot2f(wr[m][1][2], q.y, a2);
      a3 = dot2f(wr[m][1][3], q.y, a3);
      a0 = dot2f(wr[m][2][0], q.z, a0);
      a1 = dot2f(wr[m][2][1], q.z, a1);
      a2 = dot2f(wr[m][2][2], q.z, a2);
      a3 = dot2f(wr[m][2][3], q.z, a3);
      a0 = dot2f(wr[m][3][0], q.w, a0);
      a1 = dot2f(wr[m][3][1], q.w, a1);
      a2 = dot2f(wr[m][3][2], q.w, a2);
      a3 = dot2f(wr[m][3][3], q.w, a3);
    }
    a0 = wave_reduce_add(a0);
    a1 = wave_reduce_add(a1);
    a2 = wave_reduce_add(a2);
    a3 = wave_reduce_add(a3);
    if (lane == 63) {
      const float pF = a0 + wx[0] * xt + bb[0];
      const float pI = a1 + wx[1] * xt + bb[1];
      const float pU = a2 + wx[2] * xt + bb[2];
      const float pO = a3 + wx[3] * xt + bb[3];
      cell = fsig(pF) * cell + fsig(pI) * ftanh(pU);
      const float hval = fsig(pO) * ftanh(cell);
      const _Float16 hf = (_Float16)hval;
      hx16[wv] = __builtin_bit_cast(uint16_t, hf);
    }
    __syncthreads();  // barrier B
    if (tid < 4) {
      const uint32_t pk = smem[18432 + tid];  // {col 8b+2t, col 8b+2t+1} as 2xf16
      const unsigned long long val =
          (((unsigned long long)(uint32_t)(s + 1)) << 32) | (unsigned long long)pk;
      __hip_atomic_store(hbuf + (size_t)((s + 1) & 1) * NPAIR + blk * 4 + tid, val,
                         __ATOMIC_RELAXED, __HIP_MEMORY_SCOPE_AGENT);
      // owner-only hseq write: this block's 4 pairs of h(s), 16B/step
      hseq[(size_t)s * NPAIR + blk * 4 + tid] = pk;
    }
  }
#undef LDP
}

// ---------------- Phase C: wt pre-pack to f16 pairs ----------------
__global__ __launch_bounds__(256) void packwt_kernel(const float* __restrict__ wt,
                                                     uint32_t* __restrict__ wtp) {
  const int idx = blockIdx.x * 256 + threadIdx.x;
  const int p = idx >> 11;
  const int n = idx & 2047;
  wtp[idx] = packh2(wt[(size_t)(2 * p) * 2048 + n], wt[(size_t)(2 * p + 1) * 2048 + n]);
}

// ---------------- Phase D: logits GEMM (fdot2, 128x128 tile) ----------------
__global__ __launch_bounds__(256) void gemm_kernel(
    const uint32_t* __restrict__ A,  // [16384][1024] f16 pairs
    const uint32_t* __restrict__ B,  // [1024][2048] f16 pairs
    const float* __restrict__ bias, float* __restrict__ C) {
  __shared__ __align__(16) uint32_t As[16 * 132];
  __shared__ __align__(16) uint32_t Bs[16 * 132];
  const int tid = threadIdx.x;
  const int bx = blockIdx.x;
  const int m0 = (bx >> 4) * 128;
  const int n0 = (bx & 15) * 128;
  const int tm = (tid & 15) * 8;
  const int tn = (tid >> 4) * 8;
  float acc[8][8];
#pragma unroll
  for (int i = 0; i < 8; ++i)
#pragma unroll
    for (int j = 0; j < 8; ++j) acc[i][j] = 0.f;
  for (int kt = 0; kt < 64; ++kt) {
    const int p0 = kt * 16;
    __syncthreads();
#pragma unroll
    for (int r = 0; r < 8; ++r) {
      int idx = r * 256 + tid;
      int m = idx >> 4, pp = idx & 15;
      As[pp * 132 + m] = A[(size_t)(m0 + m) * 1024 + p0 + pp];
    }
#pragma unroll
    for (int r = 0; r < 8; ++r) {
      int idx = r * 256 + tid;
      int pp = idx >> 7, n = idx & 127;
      Bs[pp * 132 + n] = B[(size_t)(p0 + pp) * 2048 + n0 + n];
    }
    __syncthreads();
#pragma unroll
    for (int pp = 0; pp < 16; ++pp) {
      const uint4* ap = (const uint4*)(As + pp * 132 + tm);
      const uint4* bp = (const uint4*)(Bs + pp * 132 + tn);
      uint4 a0 = ap[0], a1 = ap[1];
      uint4 b0 = bp[0], b1 = bp[1];
      uint32_t av[8] = {a0.x, a0.y, a0.z, a0.w, a1.x, a1.y, a1.z, a1.w};
      uint32_t bv[8] = {b0.x, b0.y, b0.z, b0.w, b1.x, b1.y, b1.z, b1.w};
#pragma unroll
      for (int i = 0; i < 8; ++i)
#pragma unroll
        for (int j = 0; j < 8; ++j) acc[i][j] = dot2f(av[i], bv[j], acc[i][j]);
    }
  }
#pragma unroll
  for (int i = 0; i < 8; ++i) {
    const int m = m0 + tm + i;
    float4 o0, o1;
    o0.x = acc[i][0] + bias[n0 + tn + 0];
    o0.y = acc[i][1] + bias[n0 + tn + 1];
    o0.z = acc[i][2] + bias[n0 + tn + 2];
    o0.w = acc[i][3] + bias[n0 + tn + 3];
    o1.x = acc[i][4] + bias[n0 + tn + 4];
    o1.y = acc[i][5] + bias[n0 + tn + 5];
    o1.z = acc[i][6] + bias[n0 + tn + 6];
    o1.w = acc[i][7] + bias[n0 + tn + 7];
    *(float4*)(C + (size_t)m * 2048 + n0 + tn) = o0;
    *(float4*)(C + (size_t)m * 2048 + n0 + tn + 4) = o1;
  }
}

// ---------------- Phase E: row-wise log_softmax in place ----------------
__global__ __launch_bounds__(256) void lsm_kernel(float* __restrict__ C) {
  __shared__ float red[8];
  const int row = blockIdx.x;
  float* p = C + (size_t)row * HID;
  const int tid = threadIdx.x, lane = tid & 63, wv = tid >> 6;
  float v[8];
  float4 q0 = *(const float4*)(p + tid * 8);
  float4 q1 = *(const float4*)(p + tid * 8 + 4);
  v[0] = q0.x; v[1] = q0.y; v[2] = q0.z; v[3] = q0.w;
  v[4] = q1.x; v[5] = q1.y; v[6] = q1.z; v[7] = q1.w;
  float mx = v[0];
#pragma unroll
  for (int i = 1; i < 8; ++i) mx = fmaxf(mx, v[i]);
#pragma unroll
  for (int m = 32; m >= 1; m >>= 1) mx = fmaxf(mx, __shfl_xor(mx, m, 64));
  if (lane == 0) red[wv] = mx;
  __syncthreads();
  mx = fmaxf(fmaxf(red[0], red[1]), fmaxf(red[2], red[3]));
  float sm = 0.f;
#pragma unroll
  for (int i = 0; i < 8; ++i) {
    v[i] -= mx;
    sm += __expf(v[i]);
  }
#pragma unroll
  for (int m = 32; m >= 1; m >>= 1) sm += __shfl_xor(sm, m, 64);
  if (lane == 0) red[4 + wv] = sm;
  __syncthreads();
  sm = red[4] + red[5] + red[6] + red[7];
  const float ls = __logf(sm);
#pragma unroll
  for (int i = 0; i < 8; ++i) v[i] -= ls;
  q0.x = v[0]; q0.y = v[1]; q0.z = v[2]; q0.w = v[3];
  q1.x = v[4]; q1.y = v[5]; q1.z = v[6]; q1.w = v[7];
  *(float4*)(p + tid * 8) = q0;
  *(float4*)(p + tid * 8 + 4) = q1;
}

extern "C" void kernel_launch(void* const* d_in, const int* in_sizes, int n_in,
                              void* d_out, int out_size, void* d_ws, size_t ws_size,
                              hipStream_t stream) {
  const float* sent = (const float*)d_in[0];
  const float* fm_w = (const float*)d_in[1];
  const float* fm_b = (const float*)d_in[2];
  const float* c1w = (const float*)d_in[3];
  const float* c1b = (const float*)d_in[4];
  const float* p1w = (const float*)d_in[5];
  const float* p1b = (const float*)d_in[6];
  const float* c2w = (const float*)d_in[7];
  const float* c2b = (const float*)d_in[8];
  const float* p2w = (const float*)d_in[9];
  const float* p2b = (const float*)d_in[10];
  const float* c3w = (const float*)d_in[11];
  const float* c3b = (const float*)d_in[12];
  const float* hw = (const float*)d_in[13];
  const float* hb = (const float*)d_in[14];
  const float* wf = (const float*)d_in[15];
  const float* bf = (const float*)d_in[16];
  const float* wi = (const float*)d_in[17];
  const float* bi = (const float*)d_in[18];
  const float* wu = (const float*)d_in[19];
  const float* bu = (const float*)d_in[20];
  const float* wo = (const float*)d_in[21];
  const float* bo = (const float*)d_in[22];
  const float* wt = (const float*)d_in[23];
  const float* bt = (const float*)d_in[24];

  char* ws = (char*)d_ws;
  float* seq = (float*)ws;                                       // 64KB
  unsigned long long* hbuf = (unsigned long long*)(ws + 65536);  // 16KB (2 x 1024 u64)
  unsigned long long* lbuf = (unsigned long long*)(ws + 131072); // 128KB (8 x 2 x 1024 u64)
  uint32_t* hseq = (uint32_t*)(ws + 262144);                     // 64MB (pairs [S][1024])
  uint32_t* wtp = (uint32_t*)(ws + 262144 + (size_t)S_LEN * NPAIR * 4);  // 8MB
  float* C = (float*)d_out;

  qcnn_kernel<<<64, 256, 0, stream>>>(sent, fm_w, fm_b, c1w, c1b, p1w, p1b, c2w, c2b,
                                      p2w, p2b, c3w, c3b, hw, hb, seq, hbuf, lbuf);
  packwt_kernel<<<8192, 256, 0, stream>>>(wt, wtp);

  void* args[] = {(void*)&seq, (void*)&wf, (void*)&bf, (void*)&wi, (void*)&bi,
                  (void*)&wu, (void*)&bu, (void*)&wo, (void*)&bo,
                  (void*)&hbuf, (void*)&lbuf, (void*)&hseq};
  hipError_t rc = hipLaunchCooperativeKernel((void*)lstm_kernel, dim3(256), dim3(512),
                                             args, 0, stream);
  if (rc != hipSuccess) {
    // 128KB LDS forces 1 block/CU; grid == 256 == #CUs, so all blocks
    // are co-resident even under a plain launch.
    lstm_kernel<<<256, 512, 0, stream>>>(seq, wf, bf, wi, bi, wu, bu, wo, bo,
                                         hbuf, lbuf, hseq);
  }

  gemm_kernel<<<2048, 256, 0, stream>>>(hseq, wtp, bt, C);
  lsm_kernel<<<16384, 256, 0, stream>>>(C);
}

// Round 14
// 36146.756 us; speedup vs baseline: 1.5052x; 1.2792x over previous
//
#include <hip/hip_runtime.h>
#include <stdint.h>

#define S_LEN 16384
#define HID 2048
#define NPAIR 1024   // h pairs (2048/2)
#define NGRP 8       // XCD groups (blk % 8 under round-robin dispatch)

typedef _Float16 h2v __attribute__((ext_vector_type(2)));

__device__ __forceinline__ float dot2f(uint32_t a, uint32_t b, float c) {
#if __has_builtin(__builtin_amdgcn_fdot2)
  return __builtin_amdgcn_fdot2(__builtin_bit_cast(h2v, a), __builtin_bit_cast(h2v, b), c, false);
#else
  h2v ha = __builtin_bit_cast(h2v, a), hb = __builtin_bit_cast(h2v, b);
  return c + (float)ha[0] * (float)hb[0] + (float)ha[1] * (float)hb[1];
#endif
}

__device__ __forceinline__ uint32_t packh2(float a, float b) {
  h2v h; h[0] = (_Float16)a; h[1] = (_Float16)b;
  return __builtin_bit_cast(uint32_t, h);
}

__device__ __forceinline__ float fsig(float x) { return 1.0f / (1.0f + __expf(-x)); }
__device__ __forceinline__ float ftanh(float x) { return 2.0f / (1.0f + __expf(-2.0f * x)) - 1.0f; }

// L2-scope (sc0-only) load/store: bypass L1, served by the XCD's L2, never
// forced to MALL. Used for intra-XCD relay->consumer fanout. If producer and
// consumer are NOT on the same XCD these may never show fresh data — the
// calling loop always has an agent-scope fallback, so correctness holds.
__device__ __forceinline__ unsigned long long ld_l2(const unsigned long long* p) {
  unsigned long long v;
  asm volatile("global_load_dwordx2 %0, %1, off sc0\n\ts_waitcnt vmcnt(0)"
               : "=v"(v) : "v"(p) : "memory");
  return v;
}
__device__ __forceinline__ void st_l2(unsigned long long* p, unsigned long long v) {
  asm volatile("global_store_dwordx2 %0, %1, off sc0" : : "v"(p), "v"(v) : "memory");
}

// Wave64 sum via DPP (VALU pipe only, no DS ops). Valid result in lane 63.
__device__ __forceinline__ float wave_reduce_add(float x) {
#define DPP_STEP(ctrl)                                                                   \
  {                                                                                      \
    int t_ = __builtin_amdgcn_update_dpp(0, __builtin_bit_cast(int, x), ctrl, 0xf, 0xf, true); \
    x += __builtin_bit_cast(float, t_);                                                  \
  }
  DPP_STEP(0x111)  // row_shr:1
  DPP_STEP(0x112)  // row_shr:2
  DPP_STEP(0x114)  // row_shr:4
  DPP_STEP(0x118)  // row_shr:8
  DPP_STEP(0x142)  // row_bcast:15
  DPP_STEP(0x143)  // row_bcast:31
#undef DPP_STEP
  return x;
}

// ---------------- Phase A: QCNN MLP per token + hbuf/lbuf init ----------------
__global__ __launch_bounds__(256) void qcnn_kernel(
    const float* __restrict__ sent,
    const float* __restrict__ fm_w, const float* __restrict__ fm_b,
    const float* __restrict__ c1w, const float* __restrict__ c1b,
    const float* __restrict__ p1w, const float* __restrict__ p1b,
    const float* __restrict__ c2w, const float* __restrict__ c2b,
    const float* __restrict__ p2w, const float* __restrict__ p2b,
    const float* __restrict__ c3w, const float* __restrict__ c3b,
    const float* __restrict__ hw, const float* __restrict__ hb,
    float* __restrict__ seq, unsigned long long* __restrict__ hbuf,
    unsigned long long* __restrict__ lbuf) {
  __shared__ float w[720];
  const int tid = threadIdx.x;
  const float* srcs[14] = {fm_w, fm_b, c1w, c1b, p1w, p1b, c2w, c2b, p2w, p2b, c3w, c3b, hw, hb};
  const int offs[14] = {0, 128, 144, 400, 416, 608, 620, 668, 672, 688, 692, 708, 712, 716};
  const int cnts[14] = {128, 16, 256, 16, 192, 12, 48, 4, 16, 4, 16, 4, 4, 1};
  for (int a = 0; a < 14; ++a)
    for (int i = tid; i < cnts[a]; i += 256) w[offs[a] + i] = srcs[a][i];
  if (blockIdx.x == 0) {
    // slot = u64: (tag32 << 32) | f16x2 pair. step s consumes tag s.
    // parity0 (even steps): tag 0, h(-1)=0; parity1: invalid tag.
    for (int p = tid; p < NPAIR; p += 256) {
      hbuf[p] = 0ull;
      hbuf[NPAIR + p] = 0x7FFFFFFFull << 32;
    }
    for (int idx = tid; idx < NGRP * NPAIR; idx += 256) {
      const int g = idx >> 10, i = idx & (NPAIR - 1);
      lbuf[(size_t)(g * 2) * NPAIR + i] = 0ull;
      lbuf[(size_t)(g * 2 + 1) * NPAIR + i] = 0x7FFFFFFFull << 32;
    }
  }
  __syncthreads();
  const int t = blockIdx.x * 256 + tid;
  float x[8];
#pragma unroll
  for (int i = 0; i < 8; ++i) x[i] = sent[t * 8 + i];
  float a0[16], a1[16], a2[12], a3[4], a4[4], a5[4];
#pragma unroll
  for (int o = 0; o < 16; ++o) {
    float s = w[128 + o];
#pragma unroll
    for (int i = 0; i < 8; ++i) s += x[i] * w[i * 16 + o];
    a0[o] = ftanh(s);
  }
#pragma unroll
  for (int o = 0; o < 16; ++o) {
    float s = w[400 + o];
#pragma unroll
    for (int i = 0; i < 16; ++i) s += a0[i] * w[144 + i * 16 + o];
    a1[o] = ftanh(s);
  }
#pragma unroll
  for (int o = 0; o < 12; ++o) {
    float s = w[608 + o];
#pragma unroll
    for (int i = 0; i < 16; ++i) s += a1[i] * w[416 + i * 12 + o];
    a2[o] = ftanh(s);
  }
#pragma unroll
  for (int o = 0; o < 4; ++o) {
    float s = w[668 + o];
#pragma unroll
    for (int i = 0; i < 12; ++i) s += a2[i] * w[620 + i * 4 + o];
    a3[o] = ftanh(s);
  }
#pragma unroll
  for (int o = 0; o < 4; ++o) {
    float s = w[688 + o];
#pragma unroll
    for (int i = 0; i < 4; ++i) s += a3[i] * w[672 + i * 4 + o];
    a4[o] = ftanh(s);
  }
#pragma unroll
  for (int o = 0; o < 4; ++o) {
    float s = w[708 + o];
#pragma unroll
    for (int i = 0; i < 4; ++i) s += a4[i] * w[692 + i * 4 + o];
    a5[o] = ftanh(s);
  }
  float s = w[716];
#pragma unroll
  for (int i = 0; i < 4; ++i) s += a5[i] * w[712 + i];
  seq[t] = fsig(s);
}

// ---------------- Phase B: persistent LSTM scan (XCD relay broadcast) ----------------
// 256 blocks x 512 threads (8 waves). Wave wv owns hidden unit col = blk*8+wv.
// Weights in VGPRs. Group g = blk & 7 (round-robin => same XCD). Blocks 0..7
// are per-group relays: they poll global hbuf (agent scope, 8 MALL pollers
// device-wide instead of 2048 waves) and fan the tagged u64s into
// lbuf[g][parity] with sc0-only stores (XCD-L2-resident). Other blocks poll
// lbuf with sc0 loads (L2 RT ~250cy), alternating with agent-scope global
// checks as a placement-independent correctness fallback (no hang possible).
__global__ __launch_bounds__(512, 2) void lstm_kernel(
    const float* __restrict__ seq,
    const float* __restrict__ wfp, const float* __restrict__ bfp,
    const float* __restrict__ wip, const float* __restrict__ bip,
    const float* __restrict__ wup, const float* __restrict__ bup,
    const float* __restrict__ wop, const float* __restrict__ bop,
    unsigned long long* __restrict__ hbuf,
    unsigned long long* __restrict__ lbuf,
    uint32_t* __restrict__ hseq) {
  __shared__ __align__(16) uint32_t smem[32768];  // 128 KB
  const int tid = threadIdx.x;
  const int lane = tid & 63;
  const int wv = tid >> 6;  // 0..7
  const int blk = blockIdx.x;
  const int grp = blk & (NGRP - 1);
  const bool is_relay = (blk < NGRP);
  const int col = blk * 8 + wv;
  const float* wptr[4] = {wfp, wip, wup, wop};
  const float* bptr[4] = {bfp, bip, bup, bop};

  // ---- stage packed-f16 weights into LDS (temporary) ----
  {
    const int jj = tid & 7;
    const int sc = blk * 8 + jj;
    const int pb = tid >> 3;  // 0..63
#pragma unroll
    for (int g = 0; g < 4; ++g) {
      const float* wsp = wptr[g];
      for (int pp = 0; pp < 16; ++pp) {
        int p = pp * 64 + pb;
        float w0 = wsp[(size_t)(1 + 2 * p) * HID + sc];
        float w1 = wsp[(size_t)(2 + 2 * p) * HID + sc];
        smem[(jj * 1024 + p) * 4 + g] = packh2(w0, w1);
      }
    }
  }
  __syncthreads();
  // ---- LDS -> VGPRs: wr[m][j][g] = gate-g weight pair (256m + 4*lane + j) ----
  uint32_t wr[4][4][4];
#pragma unroll
  for (int m = 0; m < 4; ++m)
#pragma unroll
    for (int j = 0; j < 4; ++j) {
      const uint4 q = *(const uint4*)&smem[(wv * 1024 + 256 * m + 4 * lane + j) * 4];
      wr[m][j][0] = q.x; wr[m][j][1] = q.y; wr[m][j][2] = q.z; wr[m][j][3] = q.w;
    }
  float wx[4], bb[4];
#pragma unroll
  for (int g = 0; g < 4; ++g) {
    wx[g] = wptr[g][col];  // row 0 = x coefficient
    bb[g] = bptr[g][col];
  }
  __syncthreads();
  // ---- repurpose LDS: [0,64K) = seq, [64K,72K) = h pair double buffer, then hx ----
  float* seqf = (float*)smem;
  for (int i = tid; i < 4096; i += 512) ((float4*)seqf)[i] = ((const float4*)seq)[i];
  uint32_t* hlds = smem + 16384;                   // 2 x 1024 u32 pairs
  uint16_t* hx16 = (uint16_t*)(smem + 18432);      // 8 x u16
  __syncthreads();

#define LDP(p) __hip_atomic_load((p), __ATOMIC_RELAXED, __HIP_MEMORY_SCOPE_AGENT)

  float cell = 0.f;
  for (int s = 0; s < S_LEN; ++s) {
    const int slot = s & 1;
    uint32_t* hl = hlds + slot * NPAIR;
    const float xt = seqf[s];
    const uint32_t want = (uint32_t)s;
    unsigned long long hv0, hv1;
    if (is_relay) {
      // -- relay: champion global sleep-poll of my 128-pair window --
      unsigned long long* src = hbuf + (size_t)slot * NPAIR + wv * 128 + lane;
      unsigned long long h0 = LDP(src), h1 = LDP(src + 64);
      while (true) {
        const bool ok0 = ((uint32_t)(h0 >> 32) == want);
        const bool ok1 = ((uint32_t)(h1 >> 32) == want);
        if (__all(ok0 && ok1)) break;
        __builtin_amdgcn_s_sleep(1);
        if (!ok0) h0 = LDP(src);
        if (!ok1) h1 = LDP(src + 64);
      }
      // -- fan out into this XCD's local buffer (L2-resident, fire-and-forget) --
      unsigned long long* ldst = lbuf + (size_t)(grp * 2 + slot) * NPAIR + wv * 128 + lane;
      st_l2(ldst, h0);
      st_l2(ldst + 64, h1);
      hv0 = h0; hv1 = h1;
    } else {
      // -- consumer: L2-local poll with agent-scope fallback --
      const unsigned long long* lsrc =
          lbuf + (size_t)(grp * 2 + slot) * NPAIR + wv * 128 + lane;
      unsigned long long* gsrc = hbuf + (size_t)slot * NPAIR + wv * 128 + lane;
      bool d0 = false, d1 = false;
      unsigned long long h0 = 0, h1 = 0;
      while (true) {
#pragma unroll
        for (int r = 0; r < 2; ++r) {
          if (!d0) { unsigned long long t = ld_l2(lsrc);      if ((uint32_t)(t >> 32) == want) { h0 = t; d0 = true; } }
          if (!d1) { unsigned long long t = ld_l2(lsrc + 64); if ((uint32_t)(t >> 32) == want) { h1 = t; d1 = true; } }
          if (__all(d0 && d1)) goto got;
        }
        if (!d0) { unsigned long long t = LDP(gsrc);      if ((uint32_t)(t >> 32) == want) { h0 = t; d0 = true; } }
        if (!d1) { unsigned long long t = LDP(gsrc + 64); if ((uint32_t)(t >> 32) == want) { h1 = t; d1 = true; } }
        if (__all(d0 && d1)) break;
        __builtin_amdgcn_s_sleep(1);
      }
got:
      hv0 = h0; hv1 = h1;
    }
    hl[wv * 128 + lane] = (uint32_t)hv0;
    hl[wv * 128 + 64 + lane] = (uint32_t)hv1;
    __syncthreads();  // barrier A
    // -- matvec: 64 dot2 from VGPR weights, h via 4 contiguous b128 reads --
    float a0 = 0.f, a1 = 0.f, a2 = 0.f, a3 = 0.f;
#pragma unroll
    for (int m = 0; m < 4; ++m) {
      const uint4 q = *(const uint4*)&hl[256 * m + 4 * lane];
      a0 = dot2f(wr[m][0][0], q.x, a0);
      a1 = dot2f(wr[m][0][1], q.x, a1);
      a2 = dot2f(wr[m][0][2], q.x, a2);
      a3 = dot2f(wr[m][0][3], q.x, a3);
      a0 = dot2f(wr[m][1][0], q.y, a0);
      a1 = dot2f(wr[m][1][1], q.y, a1);
      a2 = dot2f(wr[m][1][2], q.y, a2);
      a3 = dot2f(wr[m][1][3], q.y, a3);
      a0 = dot2f(wr[m][2][0], q.z, a0);
      a1 = dot2f(wr[m][2][1], q.z, a1);
      a2 = dot2f(wr[m][2][2], q.z, a2);
      a3 = dot2f(wr[m][2][3], q.z, a3);
      a0 = dot2f(wr[m][3][0], q.w, a0);
      a1 = dot2f(wr[m][3][1], q.w, a1);
      a2 = dot2f(wr[m][3][2], q.w, a2);
      a3 = dot2f(wr[m][3][3], q.w, a3);
    }
    a0 = wave_reduce_add(a0);
    a1 = wave_reduce_add(a1);
    a2 = wave_reduce_add(a2);
    a3 = wave_reduce_add(a3);
    if (lane == 63) {
      const float pF = a0 + wx[0] * xt + bb[0];
      const float pI = a1 + wx[1] * xt + bb[1];
      const float pU = a2 + wx[2] * xt + bb[2];
      const float pO = a3 + wx[3] * xt + bb[3];
      cell = fsig(pF) * cell + fsig(pI) * ftanh(pU);
      const float hval = fsig(pO) * ftanh(cell);
      const _Float16 hf = (_Float16)hval;
      hx16[wv] = __builtin_bit_cast(uint16_t, hf);
    }
    __syncthreads();  // barrier B
    if (tid < 4) {
      const uint32_t pk = smem[18432 + tid];  // {col 8b+2t, col 8b+2t+1} as 2xf16
      const unsigned long long val =
          (((unsigned long long)(uint32_t)(s + 1)) << 32) | (unsigned long long)pk;
      __hip_atomic_store(hbuf + (size_t)((s + 1) & 1) * NPAIR + blk * 4 + tid, val,
                         __ATOMIC_RELAXED, __HIP_MEMORY_SCOPE_AGENT);
      // owner-only hseq write: this block's 4 pairs of h(s), 16B/step
      hseq[(size_t)s * NPAIR + blk * 4 + tid] = pk;
    }
  }
#undef LDP
}

// ---------------- Phase C: wt pre-pack to f16 pairs ----------------
__global__ __launch_bounds__(256) void packwt_kernel(const float* __restrict__ wt,
                                                     uint32_t* __restrict__ wtp) {
  const int idx = blockIdx.x * 256 + threadIdx.x;
  const int p = idx >> 11;
  const int n = idx & 2047;
  wtp[idx] = packh2(wt[(size_t)(2 * p) * 2048 + n], wt[(size_t)(2 * p + 1) * 2048 + n]);
}

// ---------------- Phase D: logits GEMM (fdot2, 128x128 tile) ----------------
__global__ __launch_bounds__(256) void gemm_kernel(
    const uint32_t* __restrict__ A,  // [16384][1024] f16 pairs
    const uint32_t* __restrict__ B,  // [1024][2048] f16 pairs
    const float* __restrict__ bias, float* __restrict__ C) {
  __shared__ __align__(16) uint32_t As[16 * 132];
  __shared__ __align__(16) uint32_t Bs[16 * 132];
  const int tid = threadIdx.x;
  const int bx = blockIdx.x;
  const int m0 = (bx >> 4) * 128;
  const int n0 = (bx & 15) * 128;
  const int tm = (tid & 15) * 8;
  const int tn = (tid >> 4) * 8;
  float acc[8][8];
#pragma unroll
  for (int i = 0; i < 8; ++i)
#pragma unroll
    for (int j = 0; j < 8; ++j) acc[i][j] = 0.f;
  for (int kt = 0; kt < 64; ++kt) {
    const int p0 = kt * 16;
    __syncthreads();
#pragma unroll
    for (int r = 0; r < 8; ++r) {
      int idx = r * 256 + tid;
      int m = idx >> 4, pp = idx & 15;
      As[pp * 132 + m] = A[(size_t)(m0 + m) * 1024 + p0 + pp];
    }
#pragma unroll
    for (int r = 0; r < 8; ++r) {
      int idx = r * 256 + tid;
      int pp = idx >> 7, n = idx & 127;
      Bs[pp * 132 + n] = B[(size_t)(p0 + pp) * 2048 + n0 + n];
    }
    __syncthreads();
#pragma unroll
    for (int pp = 0; pp < 16; ++pp) {
      const uint4* ap = (const uint4*)(As + pp * 132 + tm);
      const uint4* bp = (const uint4*)(Bs + pp * 132 + tn);
      uint4 a0 = ap[0], a1 = ap[1];
      uint4 b0 = bp[0], b1 = bp[1];
      uint32_t av[8] = {a0.x, a0.y, a0.z, a0.w, a1.x, a1.y, a1.z, a1.w};
      uint32_t bv[8] = {b0.x, b0.y, b0.z, b0.w, b1.x, b1.y, b1.z, b1.w};
#pragma unroll
      for (int i = 0; i < 8; ++i)
#pragma unroll
        for (int j = 0; j < 8; ++j) acc[i][j] = dot2f(av[i], bv[j], acc[i][j]);
    }
  }
#pragma unroll
  for (int i = 0; i < 8; ++i) {
    const int m = m0 + tm + i;
    float4 o0, o1;
    o0.x = acc[i][0] + bias[n0 + tn + 0];
    o0.y = acc[i][1] + bias[n0 + tn + 1];
    o0.z = acc[i][2] + bias[n0 + tn + 2];
    o0.w = acc[i][3] + bias[n0 + tn + 3];
    o1.x = acc[i][4] + bias[n0 + tn + 4];
    o1.y = acc[i][5] + bias[n0 + tn + 5];
    o1.z = acc[i][6] + bias[n0 + tn + 6];
    o1.w = acc[i][7] + bias[n0 + tn + 7];
    *(float4*)(C + (size_t)m * 2048 + n0 + tn) = o0;
    *(float4*)(C + (size_t)m * 2048 + n0 + tn + 4) = o1;
  }
}

// ---------------- Phase E: row-wise log_softmax in place ----------------
__global__ __launch_bounds__(256) void lsm_kernel(float* __restrict__ C) {
  __shared__ float red[8];
  const int row = blockIdx.x;
  float* p = C + (size_t)row * HID;
  const int tid = threadIdx.x, lane = tid & 63, wv = tid >> 6;
  float v[8];
  float4 q0 = *(const float4*)(p + tid * 8);
  float4 q1 = *(const float4*)(p + tid * 8 + 4);
  v[0] = q0.x; v[1] = q0.y; v[2] = q0.z; v[3] = q0.w;
  v[4] = q1.x; v[5] = q1.y; v[6] = q1.z; v[7] = q1.w;
  float mx = v[0];
#pragma unroll
  for (int i = 1; i < 8; ++i) mx = fmaxf(mx, v[i]);
#pragma unroll
  for (int m = 32; m >= 1; m >>= 1) mx = fmaxf(mx, __shfl_xor(mx, m, 64));
  if (lane == 0) red[wv] = mx;
  __syncthreads();
  mx = fmaxf(fmaxf(red[0], red[1]), fmaxf(red[2], red[3]));
  float sm = 0.f;
#pragma unroll
  for (int i = 0; i < 8; ++i) {
    v[i] -= mx;
    sm += __expf(v[i]);
  }
#pragma unroll
  for (int m = 32; m >= 1; m >>= 1) sm += __shfl_xor(sm, m, 64);
  if (lane == 0) red[4 + wv] = sm;
  __syncthreads();
  sm = red[4] + red[5] + red[6] + red[7];
  const float ls = __logf(sm);
#pragma unroll
  for (int i = 0; i < 8; ++i) v[i] -= ls;
  q0.x = v[0]; q0.y = v[1]; q0.z = v[2]; q0.w = v[3];
  q1.x = v[4]; q1.y = v[5]; q1.z = v[6]; q1.w = v[7];
  *(float4*)(p + tid * 8) = q0;
  *(float4*)(p + tid * 8 + 4) = q1;
}

extern "C" void kernel_launch(void* const* d_in, const int* in_sizes, int n_in,
                              void* d_out, int out_size, void* d_ws, size_t ws_size,
                              hipStream_t stream) {
  const float* sent = (const float*)d_in[0];
  const float* fm_w = (const float*)d_in[1];
  const float* fm_b = (const float*)d_in[2];
  const float* c1w = (const float*)d_in[3];
  const float* c1b = (const float*)d_in[4];
  const float* p1w = (const float*)d_in[5];
  const float* p1b = (const float*)d_in[6];
  const float* c2w = (const float*)d_in[7];
  const float* c2b = (const float*)d_in[8];
  const float* p2w = (const float*)d_in[9];
  const float* p2b = (const float*)d_in[10];
  const float* c3w = (const float*)d_in[11];
  const float* c3b = (const float*)d_in[12];
  const float* hw = (const float*)d_in[13];
  const float* hb = (const float*)d_in[14];
  const float* wf = (const float*)d_in[15];
  const float* bf = (const float*)d_in[16];
  const float* wi = (const float*)d_in[17];
  const float* bi = (const float*)d_in[18];
  const float* wu = (const float*)d_in[19];
  const float* bu = (const float*)d_in[20];
  const float* wo = (const float*)d_in[21];
  const float* bo = (const float*)d_in[22];
  const float* wt = (const float*)d_in[23];
  const float* bt = (const float*)d_in[24];

  char* ws = (char*)d_ws;
  float* seq = (float*)ws;                                       // 64KB
  unsigned long long* hbuf = (unsigned long long*)(ws + 65536);  // 16KB (2 x 1024 u64)
  unsigned long long* lbuf = (unsigned long long*)(ws + 131072); // 128KB (8 x 2 x 1024 u64)
  uint32_t* hseq = (uint32_t*)(ws + 262144);                     // 64MB (pairs [S][1024])
  uint32_t* wtp = (uint32_t*)(ws + 262144 + (size_t)S_LEN * NPAIR * 4);  // 8MB
  float* C = (float*)d_out;

  qcnn_kernel<<<64, 256, 0, stream>>>(sent, fm_w, fm_b, c1w, c1b, p1w, p1b, c2w, c2b,
                                      p2w, p2b, c3w, c3b, hw, hb, seq, hbuf, lbuf);
  packwt_kernel<<<8192, 256, 0, stream>>>(wt, wtp);

  void* args[] = {(void*)&seq, (void*)&wf, (void*)&bf, (void*)&wi, (void*)&bi,
                  (void*)&wu, (void*)&bu, (void*)&wo, (void*)&bo,
                  (void*)&hbuf, (void*)&lbuf, (void*)&hseq};
  hipError_t rc = hipLaunchCooperativeKernel((void*)lstm_kernel, dim3(256), dim3(512),
                                             args, 0, stream);
  if (rc != hipSuccess) {
    // 128KB LDS forces 1 block/CU; grid == 256 == #CUs, so all blocks
    // are co-resident even under a plain launch.
    lstm_kernel<<<256, 512, 0, stream>>>(seq, wf, bf, wi, bi, wu, bu, wo, bo,
                                         hbuf, lbuf, hseq);
  }

  gemm_kernel<<<2048, 256, 0, stream>>>(hseq, wtp, bt, C);
  lsm_kernel<<<16384, 256, 0, stream>>>(C);
}